// Round 10
// baseline (3313.896 us; speedup 1.0000x reference)
//
#include <hip/hip_runtime.h>
#include <math.h>

// ---------------- dims ----------------
#define B_ 8
#define T_ 4
#define C_ 12
#define H_ 128
#define W_ 256
#define P_ 128
#define S_ 512
#define D_ 768
#define NH_ 12
#define HD_ 64
#define L_ 8
#define MLP_ 3072
#define DD_ 512
#define NHD_ 8
#define LD_ 4
#define MLPD_ 2048
#define OUT_ 768

typedef __bf16 bf16x8 __attribute__((ext_vector_type(8)));
typedef float f32x4 __attribute__((ext_vector_type(4)));

static __device__ __forceinline__ unsigned short f2bf(float f) {
    unsigned int u = __float_as_uint(f);
    unsigned int r = (u + 0x7fffu + ((u >> 16) & 1u)) >> 16;
    return (unsigned short)r;
}

// fast GELU: x * sigmoid(1.59576912x + 0.07135482x^3)
static __device__ __forceinline__ float fgelu(float v) {
    float u2 = v * (1.5957691216f + 0.0713548162f * v * v);
    return __fdividef(v, 1.f + __expf(-u2));
}

#define GLDS(gp, lp) __builtin_amdgcn_global_load_lds( \
    (const __attribute__((address_space(1))) void*)(gp), \
    (__attribute__((address_space(3))) void*)(lp), 16, 0, 0)

// ---------------- small utility kernels ----------------

__global__ void mask_k(const float* __restrict__ mr, int* __restrict__ blocked) {
    int i = threadIdx.x; // 128 = L*T*T
    if (i < L_ * T_ * T_) {
        int tk = i & 3, tq = (i >> 2) & 3;
        blocked[i] = (mr[i] < 0.8f && tk > tq) ? 1 : 0;
    }
}

// batched transpose + cast: in (batch, Kd, Nd) fp32 -> out (batch, Nd, Kd) bf16
__global__ __launch_bounds__(256) void wtrans_k(const float* __restrict__ in, unsigned short* __restrict__ out,
                                                int Kd, int Nd) {
    __shared__ float tile[32][33];
    int n0 = blockIdx.x * 32, k0 = blockIdx.y * 32;
    size_t boff = (size_t)blockIdx.z * Kd * Nd;
    const float* src = in + boff;
    unsigned short* dst = out + boff;
    int tx = threadIdx.x & 31, ty = threadIdx.x >> 5; // 32 x 8
#pragma unroll
    for (int i = 0; i < 32; i += 8)
        tile[ty + i][tx] = src[(size_t)(k0 + ty + i) * Nd + n0 + tx];
    __syncthreads();
#pragma unroll
    for (int i = 0; i < 32; i += 8)
        dst[(size_t)(n0 + ty + i) * Kd + k0 + tx] = f2bf(tile[tx][ty + i]);
}

// one encoder layer: transpose all 4 weights in one launch (6912 tile-blocks)
__global__ __launch_bounds__(256) void wtransenc_k(const float* __restrict__ s0, const float* __restrict__ s1,
                                                   const float* __restrict__ s2, const float* __restrict__ s3,
                                                   unsigned short* __restrict__ d0, unsigned short* __restrict__ d1,
                                                   unsigned short* __restrict__ d2, unsigned short* __restrict__ d3) {
    __shared__ float tile[32][33];
    int bid = blockIdx.x;
    const float* src; unsigned short* dst; int Kd, Nd, tt;
    if (bid < 1728)      { src = s0; dst = d0; Kd = 768;  Nd = 2304; tt = bid; }
    else if (bid < 2304) { src = s1; dst = d1; Kd = 768;  Nd = 768;  tt = bid - 1728; }
    else if (bid < 4608) { src = s2; dst = d2; Kd = 768;  Nd = 3072; tt = bid - 2304; }
    else                 { src = s3; dst = d3; Kd = 3072; Nd = 768;  tt = bid - 4608; }
    int nT = Nd >> 5;
    int n0 = (tt % nT) * 32, k0 = (tt / nT) * 32;
    int tx = threadIdx.x & 31, ty = threadIdx.x >> 5;
#pragma unroll
    for (int i = 0; i < 32; i += 8)
        tile[ty + i][tx] = src[(size_t)(k0 + ty + i) * Nd + n0 + tx];
    __syncthreads();
#pragma unroll
    for (int i = 0; i < 32; i += 8)
        dst[(size_t)(n0 + ty + i) * Kd + k0 + tx] = f2bf(tile[tx][ty + i]);
}

// xf[bt, p, c*256+ph*16+pw] = x[bt, c, hp*16+ph, wp*16+pw]  (bf16 out)
__global__ void gather_k(const float* __restrict__ x, unsigned short* __restrict__ xf) {
    size_t i4 = ((size_t)blockIdx.x * 256 + threadIdx.x) * 4;
    if (i4 >= (size_t)4096 * 3072) return;
    int row = (int)(i4 / 3072), col = (int)(i4 % 3072);
    int bt = row >> 7, p = row & 127;
    int hp = p >> 4, wp = p & 15;
    int c = col >> 8, rem = col & 255;
    int ph = rem >> 4, pw0 = rem & 15;
    const float* src = x + (((size_t)(bt * C_ + c) * H_ + hp * 16 + ph) * W_ + wp * 16 + pw0);
    float4 v = *(const float4*)src;
    uint2 o;
    o.x = (unsigned)f2bf(v.x) | ((unsigned)f2bf(v.y) << 16);
    o.y = (unsigned)f2bf(v.z) | ((unsigned)f2bf(v.w) << 16);
    *(uint2*)(xf + i4) = o;
}

// linear cast fp32 -> bf16, n multiple of 4
__global__ void cast_k(const float* __restrict__ in, unsigned short* __restrict__ out, int n4) {
    int i = blockIdx.x * 256 + threadIdx.x;
    if (i >= n4) return;
    float4 v = *(const float4*)(in + (size_t)i * 4);
    uint2 o;
    o.x = (unsigned)f2bf(v.x) | ((unsigned)f2bf(v.y) << 16);
    o.y = (unsigned)f2bf(v.z) | ((unsigned)f2bf(v.w) << 16);
    *(uint2*)(out + (size_t)i * 4) = o;
}

// dq init + fused LN of dec_query rows
__global__ __launch_bounds__(256) void dqinitln_k(float* __restrict__ dq, unsigned short* __restrict__ ybf,
                                                  const float* __restrict__ q0,
                                                  const float* __restrict__ lns, const float* __restrict__ lnb) {
    __shared__ float rs[4], rq[4];
    int row = blockIdx.x, t = threadIdx.x;  // 1024 rows
    int p = row & 127;
    float v0 = q0[p * 512 + t], v1 = q0[p * 512 + t + 256];
    dq[(size_t)row * 512 + t] = v0;
    dq[(size_t)row * 512 + t + 256] = v1;
    float s1 = v0 + v1, s2 = v0 * v0 + v1 * v1;
    for (int o = 32; o; o >>= 1) { s1 += __shfl_xor(s1, o); s2 += __shfl_xor(s2, o); }
    if ((t & 63) == 0) { rs[t >> 6] = s1; rq[t >> 6] = s2; }
    __syncthreads();
    s1 = rs[0] + rs[1] + rs[2] + rs[3];
    s2 = rq[0] + rq[1] + rq[2] + rq[3];
    float mean = s1 / 512.f;
    float inv = rsqrtf(s2 / 512.f - mean * mean + 1e-5f);
    ybf[(size_t)row * 512 + t] = f2bf((v0 - mean) * inv * lns[t] + lnb[t]);
    ybf[(size_t)row * 512 + t + 256] = f2bf((v1 - mean) * inv * lns[t + 256] + lnb[t + 256]);
}

// ---------------- bf16 MFMA GEMM: LDS-FREE (flatmm style) ----------------
// A: MxKstride bf16 row-major (compute over Klen cols). Bt: NxKstride bf16 (= B^T).
// Tile 128x128, 4 waves, each 64x64. Fragments loaded DIRECT global->register:
// lane l of frag f reads 16B at row (base + f*16 + (l&15)), k-offset (l>>4)*8.
// Each wave load covers 16 full 64B lines (no waste); wave-pair duplicates hit L1,
// neighbor-block A panels hit L2 (XCD swizzle). No LDS, no barriers, no vmcnt drains;
// register ping-pong (a0/b0, a1/b1) gives distance-1 prefetch + compiler counted waits.
__global__ __launch_bounds__(256, 3) void mgemm_k(const unsigned short* __restrict__ A,
                                                  const unsigned short* __restrict__ Bt,
                                                  const float* __restrict__ bias,
                                                  const float* __restrict__ res,
                                                  float* Cf, unsigned short* Cb,
                                                  int N, int Kstride, int Klen, int dogelu, int resMask,
                                                  long long aBS, long long bBS, long long cBS, long long biasBS) {
    const int t = threadIdx.x, w = t >> 6, ln = t & 63;

    const int z = blockIdx.z;
    A += (size_t)z * aBS;
    Bt += (size_t)z * bBS;
    if (bias) bias += (size_t)z * biasBS;
    if (Cf) Cf += (size_t)z * cBS;
    if (Cb) Cb += (size_t)z * cBS;

    // bijective XCD swizzle (m204)
    int nwg = gridDim.x * gridDim.y;
    int orig = blockIdx.y * gridDim.x + blockIdx.x;
    int qq = nwg >> 3, rr = nwg & 7;
    int xcd = orig & 7, lid = orig >> 3;
    int swz = (xcd < rr) ? (xcd * (qq + 1) + lid) : (rr * (qq + 1) + (xcd - rr) * qq + lid);
    const int row0 = (swz / gridDim.x) * 128, col0 = (swz % gridDim.x) * 128;
    const int wr = w >> 1, wc = w & 1;
    const int rl = ln & 15, kg = ln >> 4;

    f32x4 acc[4][4] = {};

    const unsigned short* pA[4];
    const unsigned short* pB[4];
#pragma unroll
    for (int f = 0; f < 4; ++f) {
        pA[f] = A + (size_t)(row0 + wr * 64 + f * 16 + rl) * Kstride + kg * 8;
        pB[f] = Bt + (size_t)(col0 + wc * 64 + f * 16 + rl) * Kstride + kg * 8;
    }

    const int nt = Klen >> 5;  // BK=32 steps; nt is even at every call site
    bf16x8 a0[4], b0[4], a1[4], b1[4];
#pragma unroll
    for (int f = 0; f < 4; ++f) { a0[f] = *(const bf16x8*)(pA[f]);      b0[f] = *(const bf16x8*)(pB[f]); }
#pragma unroll
    for (int f = 0; f < 4; ++f) { a1[f] = *(const bf16x8*)(pA[f] + 32); b1[f] = *(const bf16x8*)(pB[f] + 32); }

    for (int tt = 0; tt < nt; tt += 2) {
#pragma unroll
        for (int i = 0; i < 4; ++i)
#pragma unroll
            for (int j = 0; j < 4; ++j)
                acc[i][j] = __builtin_amdgcn_mfma_f32_16x16x32_bf16(a0[i], b0[j], acc[i][j], 0, 0, 0);
        if (tt + 2 < nt) {
            const int koff = (tt + 2) << 5;
#pragma unroll
            for (int f = 0; f < 4; ++f) { a0[f] = *(const bf16x8*)(pA[f] + koff); b0[f] = *(const bf16x8*)(pB[f] + koff); }
        }
#pragma unroll
        for (int i = 0; i < 4; ++i)
#pragma unroll
            for (int j = 0; j < 4; ++j)
                acc[i][j] = __builtin_amdgcn_mfma_f32_16x16x32_bf16(a1[i], b1[j], acc[i][j], 0, 0, 0);
        if (tt + 3 < nt) {
            const int koff = (tt + 3) << 5;
#pragma unroll
            for (int f = 0; f < 4; ++f) { a1[f] = *(const bf16x8*)(pA[f] + koff); b1[f] = *(const bf16x8*)(pB[f] + koff); }
        }
    }

    // epilogue: C/D layout col=lane&15, row=(lane>>4)*4+reg
    const int cl = ln & 15, rg = ln >> 4;
#pragma unroll
    for (int i = 0; i < 4; ++i) {
#pragma unroll
        for (int j = 0; j < 4; ++j) {
#pragma unroll
            for (int r = 0; r < 4; ++r) {
                int row = row0 + wr * 64 + i * 16 + rg * 4 + r;
                int col = col0 + wc * 64 + j * 16 + cl;
                float v = acc[i][j][r];
                if (bias) v += bias[col];
                if (dogelu) v = fgelu(v);
                if (res) v += res[(size_t)(row & resMask) * N + col];
                if (Cf) Cf[(size_t)row * N + col] = v;
                if (Cb) Cb[(size_t)row * N + col] = f2bf(v);
            }
        }
    }
}

// ---------------- split-K reduce + epilogue (element-parallel) ----------------
__global__ __launch_bounds__(256) void redep_k(const float* __restrict__ part, int S, long long pstride,
                                               const float* __restrict__ bias, const float* __restrict__ res,
                                               float* __restrict__ Cf, unsigned short* __restrict__ Cb,
                                               int N, int dogelu, int resMask) {
    size_t i4 = ((size_t)blockIdx.x * 256 + threadIdx.x) * 4;
    int row = (int)(i4 / N), col = (int)(i4 % N);
    float4 acc = *(const float4*)(part + i4);
    for (int s = 1; s < S; ++s) {
        float4 p = *(const float4*)(part + (size_t)s * pstride + i4);
        acc.x += p.x; acc.y += p.y; acc.z += p.z; acc.w += p.w;
    }
    if (bias) {
        float4 bv = *(const float4*)(bias + col);
        acc.x += bv.x; acc.y += bv.y; acc.z += bv.z; acc.w += bv.w;
    }
    if (dogelu) {
        acc.x = fgelu(acc.x);
        acc.y = fgelu(acc.y);
        acc.z = fgelu(acc.z);
        acc.w = fgelu(acc.w);
    }
    if (res) {
        float4 rv = *(const float4*)(res + (size_t)(row & resMask) * N + col);
        acc.x += rv.x; acc.y += rv.y; acc.z += rv.z; acc.w += rv.w;
    }
    if (Cf) *(float4*)(Cf + i4) = acc;
    if (Cb) {
        uint2 o;
        o.x = (unsigned)f2bf(acc.x) | ((unsigned)f2bf(acc.y) << 16);
        o.y = (unsigned)f2bf(acc.z) | ((unsigned)f2bf(acc.w) << 16);
        *(uint2*)(Cb + i4) = o;
    }
}

// ---------------- split-K reduce + residual + fused LayerNorm (row per block) ----------------
__global__ __launch_bounds__(256) void redln_k(const float* __restrict__ part, int S, long long pstride,
                                               const float* __restrict__ bias,
                                               const float* __restrict__ res, int resMask,
                                               float* __restrict__ hout, unsigned short* __restrict__ ybf,
                                               const float* __restrict__ lns, const float* __restrict__ lnb,
                                               int N) {
    __shared__ float rs[4], rq[4];
    int row = blockIdx.x, t = threadIdx.x;
    float vbuf[3];
    float s1 = 0.f, s2 = 0.f;
    int nc = 0;
    for (int c = t; c < N; c += 256, ++nc) {
        size_t idx = (size_t)row * N + c;
        float a = part[idx];
        for (int s = 1; s < S; ++s) a += part[(size_t)s * pstride + idx];
        if (bias) a += bias[c];
        if (res) a += res[(size_t)(row & resMask) * N + c];
        if (hout) hout[idx] = a;
        vbuf[nc] = a;
        s1 += a; s2 += a * a;
    }
    if (lns) {
        for (int o = 32; o; o >>= 1) { s1 += __shfl_xor(s1, o); s2 += __shfl_xor(s2, o); }
        if ((t & 63) == 0) { rs[t >> 6] = s1; rq[t >> 6] = s2; }
        __syncthreads();
        s1 = rs[0] + rs[1] + rs[2] + rs[3];
        s2 = rq[0] + rq[1] + rq[2] + rq[3];
        float mean = s1 / N;
        float inv = rsqrtf(s2 / N - mean * mean + 1e-5f);
        nc = 0;
        for (int c = t; c < N; c += 256, ++nc)
            ybf[(size_t)row * N + c] = f2bf((vbuf[nc] - mean) * inv * lns[c] + lnb[c]);
    } else if (ybf) {
        nc = 0;
        for (int c = t; c < N; c += 256, ++nc)
            ybf[(size_t)row * N + c] = f2bf(vbuf[nc]);
    }
}

// ---------------- fused flash attention (bf16 MFMA) ----------------
__global__ __launch_bounds__(256) void fattn_k(
    const unsigned short* __restrict__ Qp, const unsigned short* __restrict__ Kp,
    const unsigned short* __restrict__ Vp, unsigned short* __restrict__ Op,
    int q_rstride, int kv_rstride, int o_rstride, int Sq, int Sk, int nh,
    float scale, const int* __restrict__ blk) {
    __shared__ unsigned short lK[64 * 64];
    __shared__ unsigned short lV[64 * 64];
    __shared__ unsigned short lP[4][16 * 64];
    const int t = threadIdx.x, wv = t >> 6, ln = t & 63;
    const int bh = blockIdx.x, b = bh / nh, hh = bh % nh;
    const int q0 = blockIdx.y * 64;
    const int tq = q0 >> 7;
    const int cl = ln & 15, rg = ln >> 4;

    bf16x8 qa[2];
    {
        const unsigned short* qrow = Qp + (size_t)(b * Sq + q0 + wv * 16 + cl) * q_rstride + hh * 64 + rg * 8;
        qa[0] = *(const bf16x8*)(qrow);
        qa[1] = *(const bf16x8*)(qrow + 32);
    }
    f32x4 oacc[4] = {};
    float mrow[4] = {-1e30f, -1e30f, -1e30f, -1e30f};
    float lrow[4] = {0.f, 0.f, 0.f, 0.f};

    int krr[2], kcc[2];
#pragma unroll
    for (int u = 0; u < 2; ++u) {
        int ch = u * 256 + t;
        krr[u] = ch >> 3;
        kcc[u] = ((ch & 7) ^ (krr[u] & 7)) << 3;
    }
    const int vk0 = (t >> 4) * 4, vd0 = (t & 15) * 4;

    for (int kc = 0; kc < Sk; kc += 64) {
        if (blk && blk[tq * 4 + (kc >> 7)]) continue;
        __syncthreads();
#pragma unroll
        for (int u = 0; u < 2; ++u)
            GLDS(Kp + (size_t)(b * Sk + kc + krr[u]) * kv_rstride + hh * 64 + kcc[u],
                 (char*)lK + ((u * 256 + wv * 64) << 4));
        {
            unsigned short a0[4], a1[4], a2[4], a3[4];
            const unsigned short* s0 = Vp + (size_t)(b * Sk + kc + vk0 + 0) * kv_rstride + hh * 64 + vd0;
            const unsigned short* s1 = Vp + (size_t)(b * Sk + kc + vk0 + 1) * kv_rstride + hh * 64 + vd0;
            const unsigned short* s2 = Vp + (size_t)(b * Sk + kc + vk0 + 2) * kv_rstride + hh * 64 + vd0;
            const unsigned short* s3 = Vp + (size_t)(b * Sk + kc + vk0 + 3) * kv_rstride + hh * 64 + vd0;
            *(uint2*)a0 = *(const uint2*)s0;
            *(uint2*)a1 = *(const uint2*)s1;
            *(uint2*)a2 = *(const uint2*)s2;
            *(uint2*)a3 = *(const uint2*)s3;
#pragma unroll
            for (int j = 0; j < 4; ++j) {
                int d = vd0 + j;
                int slot = (vk0 >> 3) ^ ((d + (d >> 3)) & 7);
                unsigned short pk[4] = {a0[j], a1[j], a2[j], a3[j]};
                *(uint2*)&lV[d * 64 + (slot << 3) + (vk0 & 7)] = *(uint2*)pk;
            }
        }
        __syncthreads();

        f32x4 sacc[4] = {};
#pragma unroll
        for (int kk = 0; kk < 2; ++kk)
#pragma unroll
            for (int f = 0; f < 4; ++f) {
                int rk = f * 16 + cl;
                bf16x8 kb = *(const bf16x8*)&lK[rk * 64 + (((kk * 4 + rg) ^ (rk & 7)) << 3)];
                sacc[f] = __builtin_amdgcn_mfma_f32_16x16x32_bf16(qa[kk], kb, sacc[f], 0, 0, 0);
            }
        float cm[4] = {-1e30f, -1e30f, -1e30f, -1e30f};
#pragma unroll
        for (int f = 0; f < 4; ++f)
#pragma unroll
            for (int r = 0; r < 4; ++r) {
                float v = sacc[f][r] * scale;
                sacc[f][r] = v;
                cm[r] = fmaxf(cm[r], v);
            }
#pragma unroll
        for (int o = 8; o; o >>= 1)
#pragma unroll
            for (int r = 0; r < 4; ++r) cm[r] = fmaxf(cm[r], __shfl_xor(cm[r], o));
        float corr[4], rsum[4];
#pragma unroll
        for (int r = 0; r < 4; ++r) {
            float nm = fmaxf(mrow[r], cm[r]);
            corr[r] = __expf(mrow[r] - nm);
            mrow[r] = nm;
            rsum[r] = 0.f;
        }
#pragma unroll
        for (int f = 0; f < 4; ++f)
#pragma unroll
            for (int r = 0; r < 4; ++r) {
                float p = __expf(sacc[f][r] - mrow[r]);
                sacc[f][r] = p;
                rsum[r] += p;
            }
#pragma unroll
        for (int o = 8; o; o >>= 1)
#pragma unroll
            for (int r = 0; r < 4; ++r) rsum[r] += __shfl_xor(rsum[r], o);
#pragma unroll
        for (int r = 0; r < 4; ++r) lrow[r] = lrow[r] * corr[r] + rsum[r];
#pragma unroll
        for (int f = 0; f < 4; ++f)
#pragma unroll
            for (int r = 0; r < 4; ++r) oacc[f][r] *= corr[r];
#pragma unroll
        for (int f = 0; f < 4; ++f)
#pragma unroll
            for (int r = 0; r < 4; ++r) {
                int q = rg * 4 + r, key = f * 16 + cl;
                lP[wv][q * 64 + (((key >> 3) ^ (q & 7)) << 3) + (key & 7)] = f2bf(sacc[f][r]);
            }
#pragma unroll
        for (int kk = 0; kk < 2; ++kk) {
            bf16x8 pa = *(const bf16x8*)&lP[wv][cl * 64 + (((kk * 4 + rg) ^ (cl & 7)) << 3)];
#pragma unroll
            for (int f = 0; f < 4; ++f) {
                int d = f * 16 + cl;
                bf16x8 vb = *(const bf16x8*)&lV[d * 64 + (((kk * 4 + rg) ^ ((d + (d >> 3)) & 7)) << 3)];
                oacc[f] = __builtin_amdgcn_mfma_f32_16x16x32_bf16(pa, vb, oacc[f], 0, 0, 0);
            }
        }
    }

    float inv[4];
#pragma unroll
    for (int r = 0; r < 4; ++r) inv[r] = 1.f / lrow[r];
#pragma unroll
    for (int f = 0; f < 4; ++f)
#pragma unroll
        for (int r = 0; r < 4; ++r) {
            int q = q0 + wv * 16 + rg * 4 + r;
            int d = f * 16 + cl;
            Op[(size_t)(b * Sq + q) * o_rstride + hh * 64 + d] = f2bf(oacc[f][r] * inv[r]);
        }
}

// ---------------- host helpers ----------------
static inline void launch_gemm(hipStream_t stream, const unsigned short* A, const unsigned short* Bt,
                               const float* bias, const float* res, float* Cf, unsigned short* Cb,
                               int M, int N, int K, int dogelu, int resMask = -1, int Z = 1,
                               long long aBS = 0, long long bBS = 0, long long cBS = 0, long long biasBS = 0) {
    hipLaunchKernelGGL(mgemm_k, dim3(N / 128, M / 128, Z), dim3(256), 0, stream,
                       A, Bt, bias, res, Cf, Cb, N, K, K, dogelu, resMask, aBS, bBS, cBS, biasBS);
}

static inline void gemm_part(hipStream_t stream, const unsigned short* A, const unsigned short* Bt,
                             float* part, int M, int N, int K, int S) {
    int Klen = K / S;
    hipLaunchKernelGGL(mgemm_k, dim3(N / 128, M / 128, S), dim3(256), 0, stream,
                       A, Bt, (const float*)nullptr, (const float*)nullptr, part, (unsigned short*)nullptr,
                       N, K, Klen, 0, -1, (long long)Klen, (long long)Klen, (long long)M * N, 0LL);
}

static inline void gemm_splitk(hipStream_t stream, const unsigned short* A, const unsigned short* Bt,
                               float* part, int M, int N, int K, int S,
                               const float* bias, const float* res, float* Cf, unsigned short* Cb,
                               int dogelu, int resMask = -1) {
    gemm_part(stream, A, Bt, part, M, N, K, S);
    hipLaunchKernelGGL(redep_k, dim3((unsigned)((size_t)M * N / 1024)), dim3(256), 0, stream,
                       part, S, (long long)M * N, bias, res, Cf, Cb, N, dogelu, resMask);
}

static inline void gemm_splitk_ln(hipStream_t stream, const unsigned short* A, const unsigned short* Bt,
                                  float* part, int M, int N, int K, int S,
                                  const float* bias, const float* res, int resMask,
                                  float* hout, unsigned short* ybf,
                                  const float* lns, const float* lnb) {
    gemm_part(stream, A, Bt, part, M, N, K, S);
    hipLaunchKernelGGL(redln_k, dim3(M), dim3(256), 0, stream,
                       part, S, (long long)M * N, bias, res, resMask, hout, ybf, lns, lnb, N);
}

extern "C" void kernel_launch(void* const* d_in, const int* in_sizes, int n_in,
                              void* d_out, int out_size, void* d_ws, size_t ws_size,
                              hipStream_t stream) {
    (void)in_sizes; (void)n_in; (void)out_size; (void)ws_size;
    const float* x          = (const float*)d_in[0];
    const float* mask_rand  = (const float*)d_in[1];
    const float* conv_w     = (const float*)d_in[2];
    const float* conv_b     = (const float*)d_in[3];
    const float* pos_emb    = (const float*)d_in[4];
    const float* enc_ln1_s  = (const float*)d_in[5];
    const float* enc_ln1_b  = (const float*)d_in[6];
    const float* enc_qkv_w  = (const float*)d_in[7];
    const float* enc_proj_w = (const float*)d_in[8];
    const float* enc_proj_b = (const float*)d_in[9];
    const float* enc_ln2_s  = (const float*)d_in[10];
    const float* enc_ln2_b  = (const float*)d_in[11];
    const float* enc_mlp_w1 = (const float*)d_in[12];
    const float* enc_mlp_b1 = (const float*)d_in[13];
    const float* enc_mlp_w2 = (const float*)d_in[14];
    const float* enc_mlp_b2 = (const float*)d_in[15];
    const float* e2d_w      = (const float*)d_in[16];
    const float* e2d_b      = (const float*)d_in[17];
    const float* dec_query  = (const float*)d_in[18];
    const float* dec_ln1_s  = (const float*)d_in[19];
    const float* dec_ln1_b  = (const float*)d_in[20];
    const float* dec_qkv_w  = (const float*)d_in[21];
    const float* dec_qkv_b  = (const float*)d_in[22];
    const float* dec_out_w  = (const float*)d_in[23];
    const float* dec_out_b  = (const float*)d_in[24];
    const float* dec_ln2_s  = (const float*)d_in[25];
    const float* dec_ln2_b  = (const float*)d_in[26];
    const float* dec_mlp_w1 = (const float*)d_in[27];
    const float* dec_mlp_b1 = (const float*)d_in[28];
    const float* dec_mlp_w2 = (const float*)d_in[29];
    const float* dec_mlp_b2 = (const float*)d_in[30];
    const float* head_ln_s  = (const float*)d_in[31];
    const float* head_ln_b  = (const float*)d_in[32];
    const float* head_w     = (const float*)d_in[33];
    const float* head_b     = (const float*)d_in[34];
    float* outp = (float*)d_out;

    // ---- workspace layout (float units) ----
    float* w = (float*)d_ws;
    size_t off = 0;
    int* blockedp = (int*)w; off += 128;
    float* h_buf = w + off; off += (size_t)4096 * 768;
    unsigned short* y_bf = (unsigned short*)(w + off); off += (size_t)4096 * 768 / 2;
    unsigned short* qkv_bf = (unsigned short*)(w + off); off += (size_t)4096 * 2304 / 2;
    unsigned short* mlp_bf = (unsigned short*)(w + off); off += (size_t)4096 * 3072 / 2;
    unsigned short* mem_bf = (unsigned short*)(w + off); off += (size_t)4096 * 512 / 2;
    float* dq_buf = w + off; off += (size_t)1024 * 512;
    unsigned short* R = (unsigned short*)(w + off); off += (size_t)16777216 / 2;  // 33.5 MB region
    unsigned short* decQkvT = (unsigned short*)(w + off); off += (size_t)12 * 262144 / 2;
    unsigned short* decOutT = (unsigned short*)(w + off); off += (size_t)4 * 262144 / 2;
    unsigned short* decMlp1T = (unsigned short*)(w + off); off += (size_t)4 * 1048576 / 2;
    unsigned short* decMlp2T = (unsigned short*)(w + off); off += (size_t)4 * 1048576 / 2;
    unsigned short* e2dT = (unsigned short*)(w + off); off += (size_t)393216 / 2;
    unsigned short* headT = (unsigned short*)(w + off); off += (size_t)393216 / 2;
    float* part_buf = w + off; off += (size_t)4 * 4096 * 768;  // split-K partials

    unsigned short* convW_bf = R;
    unsigned short* wqkvT = R;
    unsigned short* wprojT = R + (size_t)1769472;
    unsigned short* wmlp1T = R + (size_t)2359296;
    unsigned short* wmlp2T = R + (size_t)4718592;
    unsigned short* KdAll = R;
    unsigned short* VdAll = R + (size_t)8388608;

    unsigned short* xf_bf = mlp_bf;
    const float* fnull = nullptr;
    float* f32null = nullptr;
    unsigned short* bfnull = nullptr;
    const float scale = 0.125f;

    // ---- upfront prep ----
    hipLaunchKernelGGL(mask_k, dim3(1), dim3(128), 0, stream, mask_rand, blockedp);
    hipLaunchKernelGGL(wtrans_k, dim3(16, 16, 12), dim3(256), 0, stream, dec_qkv_w, decQkvT, 512, 512);
    hipLaunchKernelGGL(wtrans_k, dim3(16, 16, 4), dim3(256), 0, stream, dec_out_w, decOutT, 512, 512);
    hipLaunchKernelGGL(wtrans_k, dim3(64, 16, 4), dim3(256), 0, stream, dec_mlp_w1, decMlp1T, 512, 2048);
    hipLaunchKernelGGL(wtrans_k, dim3(16, 64, 4), dim3(256), 0, stream, dec_mlp_w2, decMlp2T, 2048, 512);
    hipLaunchKernelGGL(wtrans_k, dim3(16, 24, 1), dim3(256), 0, stream, e2d_w, e2dT, 768, 512);
    hipLaunchKernelGGL(wtrans_k, dim3(24, 16, 1), dim3(256), 0, stream, head_w, headT, 512, 768);
    hipLaunchKernelGGL(cast_k, dim3((768 * 3072 / 4 + 255) / 256), dim3(256), 0, stream,
                       conv_w, convW_bf, 768 * 3072 / 4);
    hipLaunchKernelGGL(gather_k, dim3(12288), dim3(256), 0, stream, x, xf_bf);
    // patchify (split-K 4) + bias + pos_emb + fused LN1(layer 0)
    gemm_splitk_ln(stream, xf_bf, convW_bf, part_buf, 4096, 768, 3072, 4,
                   conv_b, pos_emb, 511, h_buf, y_bf, enc_ln1_s, enc_ln1_b);

    // -------- encoder --------
    for (int l = 0; l < L_; ++l) {
        const int* blk = blockedp + l * 16;
        hipLaunchKernelGGL(wtransenc_k, dim3(6912), dim3(256), 0, stream,
                           enc_qkv_w + (size_t)l * 768 * 2304, enc_proj_w + (size_t)l * 768 * 768,
                           enc_mlp_w1 + (size_t)l * 768 * 3072, enc_mlp_w2 + (size_t)l * 3072 * 768,
                           wqkvT, wprojT, wmlp1T, wmlp2T);
        launch_gemm(stream, y_bf, wqkvT, fnull, fnull, f32null, qkv_bf, 4096, 2304, 768, 0);
        hipLaunchKernelGGL(fattn_k, dim3(B_ * NH_, S_ / 64), dim3(256), 0, stream,
                           qkv_bf, qkv_bf + 768, qkv_bf + 1536, y_bf,
                           2304, 2304, 768, S_, S_, NH_, scale, blk);
        // proj: split-K 2, res=h, fused LN2 -> y_bf
        gemm_splitk_ln(stream, y_bf, wprojT, part_buf, 4096, 768, 768, 2,
                       enc_proj_b + l * 768, h_buf, -1, h_buf, y_bf,
                       enc_ln2_s + l * 768, enc_ln2_b + l * 768);
        launch_gemm(stream, y_bf, wmlp1T, enc_mlp_b1 + l * 3072, fnull, f32null, mlp_bf, 4096, 3072, 768, 1);
        // mlp2: split-K 4, res=h, fused next-LN1 (raw cast on last layer)
        gemm_splitk_ln(stream, mlp_bf, wmlp2T, part_buf, 4096, 768, 3072, 4,
                       enc_mlp_b2 + l * 768, h_buf, -1, h_buf, y_bf,
                       (l < L_ - 1) ? (enc_ln1_s + (l + 1) * 768) : fnull,
                       (l < L_ - 1) ? (enc_ln1_b + (l + 1) * 768) : fnull);
    }

    // -------- enc2dec --------
    gemm_splitk(stream, y_bf, e2dT, part_buf, 4096, 512, 768, 2,
                e2d_b, fnull, f32null, mem_bf, 0);
    hipLaunchKernelGGL(dqinitln_k, dim3(1024), dim3(256), 0, stream,
                       dq_buf, y_bf, dec_query, dec_ln1_s, dec_ln1_b);
    launch_gemm(stream, mem_bf, decQkvT + (size_t)262144, dec_qkv_b + 512, fnull, f32null, KdAll,
                4096, 512, 512, 0, -1, 4, 0, 3LL * 262144, 4096LL * 512, 3LL * 512);
    launch_gemm(stream, mem_bf, decQkvT + (size_t)2 * 262144, dec_qkv_b + 2 * 512, fnull, f32null, VdAll,
                4096, 512, 512, 0, -1, 4, 0, 3LL * 262144, 4096LL * 512, 3LL * 512);

    // -------- decoder --------
    unsigned short* Qd = qkv_bf;
    for (int l = 0; l < LD_; ++l) {
        unsigned short* Kd = KdAll + (size_t)l * 4096 * 512;
        unsigned short* Vd = VdAll + (size_t)l * 4096 * 512;
        gemm_splitk(stream, y_bf, decQkvT + (size_t)(l * 3) * 262144, part_buf, 1024, 512, 512, 4,
                    dec_qkv_b + (l * 3) * 512, fnull, f32null, Qd, 0);
        hipLaunchKernelGGL(fattn_k, dim3(B_ * NHD_, P_ / 64), dim3(256), 0, stream,
                           Qd, Kd, Vd, y_bf, 512, 512, 512, P_, S_, NHD_, scale, (const int*)nullptr);
        // out: split-K 4, res=dq, fused LN2 -> y_bf
        gemm_splitk_ln(stream, y_bf, decOutT + (size_t)l * 262144, part_buf, 1024, 512, 512, 4,
                       dec_out_b + l * 512, dq_buf, -1, dq_buf, y_bf,
                       dec_ln2_s + l * 512, dec_ln2_b + l * 512);
        gemm_splitk(stream, y_bf, decMlp1T + (size_t)l * 1048576, part_buf, 1024, 2048, 512, 2,
                    dec_mlp_b1 + l * 2048, fnull, f32null, mlp_bf, 1);
        // mlp2: split-K 8, res=dq, fused next-LN1 (head_ln on last)
        gemm_splitk_ln(stream, mlp_bf, decMlp2T + (size_t)l * 1048576, part_buf, 1024, 512, 2048, 8,
                       dec_mlp_b2 + l * 512, dq_buf, -1, dq_buf, y_bf,
                       (l < LD_ - 1) ? (dec_ln1_s + (l + 1) * 512) : head_ln_s,
                       (l < LD_ - 1) ? (dec_ln1_b + (l + 1) * 512) : head_ln_b);
    }

    // -------- head --------
    gemm_splitk(stream, y_bf, headT, part_buf, 1024, 768, 512, 4,
                head_b, fnull, outp, bfnull, 0);
}

// Round 11
// 2520.985 us; speedup vs baseline: 1.3145x; 1.3145x over previous
//
#include <hip/hip_runtime.h>
#include <math.h>

// ---------------- dims ----------------
#define B_ 8
#define T_ 4
#define C_ 12
#define H_ 128
#define W_ 256
#define P_ 128
#define S_ 512
#define D_ 768
#define NH_ 12
#define HD_ 64
#define L_ 8
#define MLP_ 3072
#define DD_ 512
#define NHD_ 8
#define LD_ 4
#define MLPD_ 2048
#define OUT_ 768

typedef __bf16 bf16x8 __attribute__((ext_vector_type(8)));
typedef float f32x4 __attribute__((ext_vector_type(4)));

static __device__ __forceinline__ unsigned short f2bf(float f) {
    unsigned int u = __float_as_uint(f);
    unsigned int r = (u + 0x7fffu + ((u >> 16) & 1u)) >> 16;
    return (unsigned short)r;
}

// fast GELU: x * sigmoid(1.59576912x + 0.07135482x^3)
static __device__ __forceinline__ float fgelu(float v) {
    float u2 = v * (1.5957691216f + 0.0713548162f * v * v);
    return __fdividef(v, 1.f + __expf(-u2));
}

#define GLDS(gp, lp) __builtin_amdgcn_global_load_lds( \
    (const __attribute__((address_space(1))) void*)(gp), \
    (__attribute__((address_space(3))) void*)(lp), 16, 0, 0)

// ---------------- small utility kernels ----------------

__global__ void mask_k(const float* __restrict__ mr, int* __restrict__ blocked) {
    int i = threadIdx.x; // 128 = L*T*T
    if (i < L_ * T_ * T_) {
        int tk = i & 3, tq = (i >> 2) & 3;
        blocked[i] = (mr[i] < 0.8f && tk > tq) ? 1 : 0;
    }
}

// batched transpose + cast: in (batch, Kd, Nd) fp32 -> out (batch, Nd, Kd) bf16
__global__ __launch_bounds__(256) void wtrans_k(const float* __restrict__ in, unsigned short* __restrict__ out,
                                                int Kd, int Nd) {
    __shared__ float tile[32][33];
    int n0 = blockIdx.x * 32, k0 = blockIdx.y * 32;
    size_t boff = (size_t)blockIdx.z * Kd * Nd;
    const float* src = in + boff;
    unsigned short* dst = out + boff;
    int tx = threadIdx.x & 31, ty = threadIdx.x >> 5; // 32 x 8
#pragma unroll
    for (int i = 0; i < 32; i += 8)
        tile[ty + i][tx] = src[(size_t)(k0 + ty + i) * Nd + n0 + tx];
    __syncthreads();
#pragma unroll
    for (int i = 0; i < 32; i += 8)
        dst[(size_t)(n0 + ty + i) * Kd + k0 + tx] = f2bf(tile[tx][ty + i]);
}

// one encoder layer: transpose all 4 weights in one launch (6912 tile-blocks)
__global__ __launch_bounds__(256) void wtransenc_k(const float* __restrict__ s0, const float* __restrict__ s1,
                                                   const float* __restrict__ s2, const float* __restrict__ s3,
                                                   unsigned short* __restrict__ d0, unsigned short* __restrict__ d1,
                                                   unsigned short* __restrict__ d2, unsigned short* __restrict__ d3) {
    __shared__ float tile[32][33];
    int bid = blockIdx.x;
    const float* src; unsigned short* dst; int Kd, Nd, tt;
    if (bid < 1728)      { src = s0; dst = d0; Kd = 768;  Nd = 2304; tt = bid; }
    else if (bid < 2304) { src = s1; dst = d1; Kd = 768;  Nd = 768;  tt = bid - 1728; }
    else if (bid < 4608) { src = s2; dst = d2; Kd = 768;  Nd = 3072; tt = bid - 2304; }
    else                 { src = s3; dst = d3; Kd = 3072; Nd = 768;  tt = bid - 4608; }
    int nT = Nd >> 5;
    int n0 = (tt % nT) * 32, k0 = (tt / nT) * 32;
    int tx = threadIdx.x & 31, ty = threadIdx.x >> 5;
#pragma unroll
    for (int i = 0; i < 32; i += 8)
        tile[ty + i][tx] = src[(size_t)(k0 + ty + i) * Nd + n0 + tx];
    __syncthreads();
#pragma unroll
    for (int i = 0; i < 32; i += 8)
        dst[(size_t)(n0 + ty + i) * Kd + k0 + tx] = f2bf(tile[tx][ty + i]);
}

// xf[bt, p, c*256+ph*16+pw] = x[bt, c, hp*16+ph, wp*16+pw]  (bf16 out)
__global__ void gather_k(const float* __restrict__ x, unsigned short* __restrict__ xf) {
    size_t i4 = ((size_t)blockIdx.x * 256 + threadIdx.x) * 4;
    if (i4 >= (size_t)4096 * 3072) return;
    int row = (int)(i4 / 3072), col = (int)(i4 % 3072);
    int bt = row >> 7, p = row & 127;
    int hp = p >> 4, wp = p & 15;
    int c = col >> 8, rem = col & 255;
    int ph = rem >> 4, pw0 = rem & 15;
    const float* src = x + (((size_t)(bt * C_ + c) * H_ + hp * 16 + ph) * W_ + wp * 16 + pw0);
    float4 v = *(const float4*)src;
    uint2 o;
    o.x = (unsigned)f2bf(v.x) | ((unsigned)f2bf(v.y) << 16);
    o.y = (unsigned)f2bf(v.z) | ((unsigned)f2bf(v.w) << 16);
    *(uint2*)(xf + i4) = o;
}

// linear cast fp32 -> bf16, n multiple of 4
__global__ void cast_k(const float* __restrict__ in, unsigned short* __restrict__ out, int n4) {
    int i = blockIdx.x * 256 + threadIdx.x;
    if (i >= n4) return;
    float4 v = *(const float4*)(in + (size_t)i * 4);
    uint2 o;
    o.x = (unsigned)f2bf(v.x) | ((unsigned)f2bf(v.y) << 16);
    o.y = (unsigned)f2bf(v.z) | ((unsigned)f2bf(v.w) << 16);
    *(uint2*)(out + (size_t)i * 4) = o;
}

// dq init + fused LN of dec_query rows
__global__ __launch_bounds__(256) void dqinitln_k(float* __restrict__ dq, unsigned short* __restrict__ ybf,
                                                  const float* __restrict__ q0,
                                                  const float* __restrict__ lns, const float* __restrict__ lnb) {
    __shared__ float rs[4], rq[4];
    int row = blockIdx.x, t = threadIdx.x;  // 1024 rows
    int p = row & 127;
    float v0 = q0[p * 512 + t], v1 = q0[p * 512 + t + 256];
    dq[(size_t)row * 512 + t] = v0;
    dq[(size_t)row * 512 + t + 256] = v1;
    float s1 = v0 + v1, s2 = v0 * v0 + v1 * v1;
    for (int o = 32; o; o >>= 1) { s1 += __shfl_xor(s1, o); s2 += __shfl_xor(s2, o); }
    if ((t & 63) == 0) { rs[t >> 6] = s1; rq[t >> 6] = s2; }
    __syncthreads();
    s1 = rs[0] + rs[1] + rs[2] + rs[3];
    s2 = rq[0] + rq[1] + rq[2] + rq[3];
    float mean = s1 / 512.f;
    float inv = rsqrtf(s2 / 512.f - mean * mean + 1e-5f);
    ybf[(size_t)row * 512 + t] = f2bf((v0 - mean) * inv * lns[t] + lnb[t]);
    ybf[(size_t)row * 512 + t + 256] = f2bf((v1 - mean) * inv * lns[t + 256] + lnb[t + 256]);
}

// ---------------- bf16 MFMA GEMM: 256x128 tile, BK=32, 2-stage, single barrier/step ----------------
// A: MxKstride bf16 row-major (compute over Klen cols). Bt: NxKstride bf16 (= B^T).
// 4 waves, each owns a 128x64 sub-tile (acc[8][4]) -> 32 MFMA/wave/step, same barrier
// cadence as the proven r7 structure but 2x compute per sync. LDS 48KB (2 stages).
// M%256==0, N%128==0, Klen%32==0.
__global__ __launch_bounds__(256, 2) void mgemm_k(const unsigned short* __restrict__ A,
                                                  const unsigned short* __restrict__ Bt,
                                                  const float* __restrict__ bias,
                                                  const float* __restrict__ res,
                                                  float* Cf, unsigned short* Cb,
                                                  int N, int Kstride, int Klen, int dogelu, int resMask,
                                                  long long aBS, long long bBS, long long cBS, long long biasBS) {
    __shared__ unsigned short lA[2][256 * 32];
    __shared__ unsigned short lB[2][128 * 32];
    const int t = threadIdx.x, w = t >> 6, ln = t & 63;

    const int z = blockIdx.z;
    A += (size_t)z * aBS;
    Bt += (size_t)z * bBS;
    if (bias) bias += (size_t)z * biasBS;
    if (Cf) Cf += (size_t)z * cBS;
    if (Cb) Cb += (size_t)z * cBS;

    // bijective XCD swizzle (m204)
    int nwg = gridDim.x * gridDim.y;
    int orig = blockIdx.y * gridDim.x + blockIdx.x;
    int qq = nwg >> 3, rr = nwg & 7;
    int xcd = orig & 7, lid = orig >> 3;
    int swz = (xcd < rr) ? (xcd * (qq + 1) + lid) : (rr * (qq + 1) + (xcd - rr) * qq + lid);
    const int row0 = (swz / gridDim.x) * 256, col0 = (swz % gridDim.x) * 128;
    const int wr = w >> 1, wc = w & 1;

    f32x4 acc[8][4] = {};

    // staging: A = 1024 chunks (4/thread), B = 512 chunks (2/thread); 16B per chunk.
    // LDS linear chunk ch -> source (ra, c4*8..+7), inverse of the read swizzle.
    const unsigned short* gA[4];
    const unsigned short* gB[2];
    int ldsOffA[4], ldsOffB[2];
#pragma unroll
    for (int u = 0; u < 4; ++u) {
        int ch = u * 256 + w * 64 + ln;          // 0..1023
        int r2 = ch >> 3, sl = ch & 7;
        int inv = sl ^ (r2 & 7);
        int ra = (r2 << 1) | (inv >> 2), c4 = inv & 3;
        gA[u] = A + (size_t)(row0 + ra) * Kstride + (c4 << 3);
        ldsOffA[u] = (u * 256 + w * 64) << 4;
    }
#pragma unroll
    for (int u = 0; u < 2; ++u) {
        int ch = u * 256 + w * 64 + ln;          // 0..511
        int r2 = ch >> 3, sl = ch & 7;
        int inv = sl ^ (r2 & 7);
        int ra = (r2 << 1) | (inv >> 2), c4 = inv & 3;
        gB[u] = Bt + (size_t)(col0 + ra) * Kstride + (c4 << 3);
        ldsOffB[u] = (u * 256 + w * 64) << 4;
    }
    // fragment read byte offsets: 2 rows per 128B line, 8x16B slots, slot XOR (r2&7)
    int offA[8], offB[4];
    {
        int s = ln >> 4;
#pragma unroll
        for (int f = 0; f < 8; ++f) {
            int ra = wr * 128 + f * 16 + (ln & 15);
            offA[f] = (ra >> 1) * 128 + ((((((ra & 1) << 2) | s)) ^ ((ra >> 1) & 7)) << 4);
        }
#pragma unroll
        for (int f = 0; f < 4; ++f) {
            int rb = wc * 64 + f * 16 + (ln & 15);
            offB[f] = (rb >> 1) * 128 + ((((((rb & 1) << 2) | s)) ^ ((rb >> 1) & 7)) << 4);
        }
    }

    const int nt = Klen >> 5;   // BK=32 steps (nt >= 4 at all call sites)
    // prologue: stage 0 into buffer 0
#pragma unroll
    for (int u = 0; u < 4; ++u) GLDS(gA[u], (char*)&lA[0][0] + ldsOffA[u]);
#pragma unroll
    for (int u = 0; u < 2; ++u) GLDS(gB[u], (char*)&lB[0][0] + ldsOffB[u]);

    for (int tt = 0; tt < nt; ++tt) {
        const int cur = tt & 1;
        asm volatile("s_waitcnt vmcnt(0)" ::: "memory");  // own stage-tt loads landed
        __builtin_amdgcn_s_barrier();                     // all waves' stage-tt in LDS;
                                                          // stage-(tt-1) reads all retired
        __builtin_amdgcn_sched_barrier(0);
        if (tt + 1 < nt) {                                // prefetch into buffer read at tt-1
            const int koff = (tt + 1) << 5;
#pragma unroll
            for (int u = 0; u < 4; ++u) GLDS(gA[u] + koff, (char*)&lA[cur ^ 1][0] + ldsOffA[u]);
#pragma unroll
            for (int u = 0; u < 2; ++u) GLDS(gB[u] + koff, (char*)&lB[cur ^ 1][0] + ldsOffB[u]);
        }
        bf16x8 av[8], bv[4];
#pragma unroll
        for (int f = 0; f < 8; ++f)
            av[f] = *(const bf16x8*)((const char*)&lA[cur][0] + offA[f]);
#pragma unroll
        for (int f = 0; f < 4; ++f)
            bv[f] = *(const bf16x8*)((const char*)&lB[cur][0] + offB[f]);
#pragma unroll
        for (int i = 0; i < 8; ++i)
#pragma unroll
            for (int j = 0; j < 4; ++j)
                acc[i][j] = __builtin_amdgcn_mfma_f32_16x16x32_bf16(av[i], bv[j], acc[i][j], 0, 0, 0);
    }

    // epilogue: C/D layout col=lane&15, row=(lane>>4)*4+reg
    const int cl = ln & 15, rg = ln >> 4;
#pragma unroll
    for (int i = 0; i < 8; ++i) {
#pragma unroll
        for (int j = 0; j < 4; ++j) {
#pragma unroll
            for (int r = 0; r < 4; ++r) {
                int row = row0 + wr * 128 + i * 16 + rg * 4 + r;
                int col = col0 + wc * 64 + j * 16 + cl;
                float v = acc[i][j][r];
                if (bias) v += bias[col];
                if (dogelu) v = fgelu(v);
                if (res) v += res[(size_t)(row & resMask) * N + col];
                if (Cf) Cf[(size_t)row * N + col] = v;
                if (Cb) Cb[(size_t)row * N + col] = f2bf(v);
            }
        }
    }
}

// ---------------- split-K reduce + epilogue (element-parallel) ----------------
__global__ __launch_bounds__(256) void redep_k(const float* __restrict__ part, int S, long long pstride,
                                               const float* __restrict__ bias, const float* __restrict__ res,
                                               float* __restrict__ Cf, unsigned short* __restrict__ Cb,
                                               int N, int dogelu, int resMask) {
    size_t i4 = ((size_t)blockIdx.x * 256 + threadIdx.x) * 4;
    int row = (int)(i4 / N), col = (int)(i4 % N);
    float4 acc = *(const float4*)(part + i4);
    for (int s = 1; s < S; ++s) {
        float4 p = *(const float4*)(part + (size_t)s * pstride + i4);
        acc.x += p.x; acc.y += p.y; acc.z += p.z; acc.w += p.w;
    }
    if (bias) {
        float4 bv = *(const float4*)(bias + col);
        acc.x += bv.x; acc.y += bv.y; acc.z += bv.z; acc.w += bv.w;
    }
    if (dogelu) {
        acc.x = fgelu(acc.x);
        acc.y = fgelu(acc.y);
        acc.z = fgelu(acc.z);
        acc.w = fgelu(acc.w);
    }
    if (res) {
        float4 rv = *(const float4*)(res + (size_t)(row & resMask) * N + col);
        acc.x += rv.x; acc.y += rv.y; acc.z += rv.z; acc.w += rv.w;
    }
    if (Cf) *(float4*)(Cf + i4) = acc;
    if (Cb) {
        uint2 o;
        o.x = (unsigned)f2bf(acc.x) | ((unsigned)f2bf(acc.y) << 16);
        o.y = (unsigned)f2bf(acc.z) | ((unsigned)f2bf(acc.w) << 16);
        *(uint2*)(Cb + i4) = o;
    }
}

// ---------------- split-K reduce + residual + fused LayerNorm (row per block) ----------------
__global__ __launch_bounds__(256) void redln_k(const float* __restrict__ part, int S, long long pstride,
                                               const float* __restrict__ bias,
                                               const float* __restrict__ res, int resMask,
                                               float* __restrict__ hout, unsigned short* __restrict__ ybf,
                                               const float* __restrict__ lns, const float* __restrict__ lnb,
                                               int N) {
    __shared__ float rs[4], rq[4];
    int row = blockIdx.x, t = threadIdx.x;
    float vbuf[3];
    float s1 = 0.f, s2 = 0.f;
    int nc = 0;
    for (int c = t; c < N; c += 256, ++nc) {
        size_t idx = (size_t)row * N + c;
        float a = part[idx];
        for (int s = 1; s < S; ++s) a += part[(size_t)s * pstride + idx];
        if (bias) a += bias[c];
        if (res) a += res[(size_t)(row & resMask) * N + c];
        if (hout) hout[idx] = a;
        vbuf[nc] = a;
        s1 += a; s2 += a * a;
    }
    if (lns) {
        for (int o = 32; o; o >>= 1) { s1 += __shfl_xor(s1, o); s2 += __shfl_xor(s2, o); }
        if ((t & 63) == 0) { rs[t >> 6] = s1; rq[t >> 6] = s2; }
        __syncthreads();
        s1 = rs[0] + rs[1] + rs[2] + rs[3];
        s2 = rq[0] + rq[1] + rq[2] + rq[3];
        float mean = s1 / N;
        float inv = rsqrtf(s2 / N - mean * mean + 1e-5f);
        nc = 0;
        for (int c = t; c < N; c += 256, ++nc)
            ybf[(size_t)row * N + c] = f2bf((vbuf[nc] - mean) * inv * lns[c] + lnb[c]);
    } else if (ybf) {
        nc = 0;
        for (int c = t; c < N; c += 256, ++nc)
            ybf[(size_t)row * N + c] = f2bf(vbuf[nc]);
    }
}

// ---------------- fused flash attention (bf16 MFMA) ----------------
__global__ __launch_bounds__(256) void fattn_k(
    const unsigned short* __restrict__ Qp, const unsigned short* __restrict__ Kp,
    const unsigned short* __restrict__ Vp, unsigned short* __restrict__ Op,
    int q_rstride, int kv_rstride, int o_rstride, int Sq, int Sk, int nh,
    float scale, const int* __restrict__ blk) {
    __shared__ unsigned short lK[64 * 64];
    __shared__ unsigned short lV[64 * 64];
    __shared__ unsigned short lP[4][16 * 64];
    const int t = threadIdx.x, wv = t >> 6, ln = t & 63;
    const int bh = blockIdx.x, b = bh / nh, hh = bh % nh;
    const int q0 = blockIdx.y * 64;
    const int tq = q0 >> 7;
    const int cl = ln & 15, rg = ln >> 4;

    bf16x8 qa[2];
    {
        const unsigned short* qrow = Qp + (size_t)(b * Sq + q0 + wv * 16 + cl) * q_rstride + hh * 64 + rg * 8;
        qa[0] = *(const bf16x8*)(qrow);
        qa[1] = *(const bf16x8*)(qrow + 32);
    }
    f32x4 oacc[4] = {};
    float mrow[4] = {-1e30f, -1e30f, -1e30f, -1e30f};
    float lrow[4] = {0.f, 0.f, 0.f, 0.f};

    int krr[2], kcc[2];
#pragma unroll
    for (int u = 0; u < 2; ++u) {
        int ch = u * 256 + t;
        krr[u] = ch >> 3;
        kcc[u] = ((ch & 7) ^ (krr[u] & 7)) << 3;
    }
    const int vk0 = (t >> 4) * 4, vd0 = (t & 15) * 4;

    for (int kc = 0; kc < Sk; kc += 64) {
        if (blk && blk[tq * 4 + (kc >> 7)]) continue;
        __syncthreads();
#pragma unroll
        for (int u = 0; u < 2; ++u)
            GLDS(Kp + (size_t)(b * Sk + kc + krr[u]) * kv_rstride + hh * 64 + kcc[u],
                 (char*)lK + ((u * 256 + wv * 64) << 4));
        {
            unsigned short a0[4], a1[4], a2[4], a3[4];
            const unsigned short* s0 = Vp + (size_t)(b * Sk + kc + vk0 + 0) * kv_rstride + hh * 64 + vd0;
            const unsigned short* s1 = Vp + (size_t)(b * Sk + kc + vk0 + 1) * kv_rstride + hh * 64 + vd0;
            const unsigned short* s2 = Vp + (size_t)(b * Sk + kc + vk0 + 2) * kv_rstride + hh * 64 + vd0;
            const unsigned short* s3 = Vp + (size_t)(b * Sk + kc + vk0 + 3) * kv_rstride + hh * 64 + vd0;
            *(uint2*)a0 = *(const uint2*)s0;
            *(uint2*)a1 = *(const uint2*)s1;
            *(uint2*)a2 = *(const uint2*)s2;
            *(uint2*)a3 = *(const uint2*)s3;
#pragma unroll
            for (int j = 0; j < 4; ++j) {
                int d = vd0 + j;
                int slot = (vk0 >> 3) ^ ((d + (d >> 3)) & 7);
                unsigned short pk[4] = {a0[j], a1[j], a2[j], a3[j]};
                *(uint2*)&lV[d * 64 + (slot << 3) + (vk0 & 7)] = *(uint2*)pk;
            }
        }
        __syncthreads();

        f32x4 sacc[4] = {};
#pragma unroll
        for (int kk = 0; kk < 2; ++kk)
#pragma unroll
            for (int f = 0; f < 4; ++f) {
                int rk = f * 16 + cl;
                bf16x8 kb = *(const bf16x8*)&lK[rk * 64 + (((kk * 4 + rg) ^ (rk & 7)) << 3)];
                sacc[f] = __builtin_amdgcn_mfma_f32_16x16x32_bf16(qa[kk], kb, sacc[f], 0, 0, 0);
            }
        float cm[4] = {-1e30f, -1e30f, -1e30f, -1e30f};
#pragma unroll
        for (int f = 0; f < 4; ++f)
#pragma unroll
            for (int r = 0; r < 4; ++r) {
                float v = sacc[f][r] * scale;
                sacc[f][r] = v;
                cm[r] = fmaxf(cm[r], v);
            }
#pragma unroll
        for (int o = 8; o; o >>= 1)
#pragma unroll
            for (int r = 0; r < 4; ++r) cm[r] = fmaxf(cm[r], __shfl_xor(cm[r], o));
        float corr[4], rsum[4];
#pragma unroll
        for (int r = 0; r < 4; ++r) {
            float nm = fmaxf(mrow[r], cm[r]);
            corr[r] = __expf(mrow[r] - nm);
            mrow[r] = nm;
            rsum[r] = 0.f;
        }
#pragma unroll
        for (int f = 0; f < 4; ++f)
#pragma unroll
            for (int r = 0; r < 4; ++r) {
                float p = __expf(sacc[f][r] - mrow[r]);
                sacc[f][r] = p;
                rsum[r] += p;
            }
#pragma unroll
        for (int o = 8; o; o >>= 1)
#pragma unroll
            for (int r = 0; r < 4; ++r) rsum[r] += __shfl_xor(rsum[r], o);
#pragma unroll
        for (int r = 0; r < 4; ++r) lrow[r] = lrow[r] * corr[r] + rsum[r];
#pragma unroll
        for (int f = 0; f < 4; ++f)
#pragma unroll
            for (int r = 0; r < 4; ++r) oacc[f][r] *= corr[r];
#pragma unroll
        for (int f = 0; f < 4; ++f)
#pragma unroll
            for (int r = 0; r < 4; ++r) {
                int q = rg * 4 + r, key = f * 16 + cl;
                lP[wv][q * 64 + (((key >> 3) ^ (q & 7)) << 3) + (key & 7)] = f2bf(sacc[f][r]);
            }
#pragma unroll
        for (int kk = 0; kk < 2; ++kk) {
            bf16x8 pa = *(const bf16x8*)&lP[wv][cl * 64 + (((kk * 4 + rg) ^ (cl & 7)) << 3)];
#pragma unroll
            for (int f = 0; f < 4; ++f) {
                int d = f * 16 + cl;
                bf16x8 vb = *(const bf16x8*)&lV[d * 64 + (((kk * 4 + rg) ^ ((d + (d >> 3)) & 7)) << 3)];
                oacc[f] = __builtin_amdgcn_mfma_f32_16x16x32_bf16(pa, vb, oacc[f], 0, 0, 0);
            }
        }
    }

    float inv[4];
#pragma unroll
    for (int r = 0; r < 4; ++r) inv[r] = 1.f / lrow[r];
#pragma unroll
    for (int f = 0; f < 4; ++f)
#pragma unroll
        for (int r = 0; r < 4; ++r) {
            int q = q0 + wv * 16 + rg * 4 + r;
            int d = f * 16 + cl;
            Op[(size_t)(b * Sq + q) * o_rstride + hh * 64 + d] = f2bf(oacc[f][r] * inv[r]);
        }
}

// ---------------- host helpers ----------------
static inline void launch_gemm(hipStream_t stream, const unsigned short* A, const unsigned short* Bt,
                               const float* bias, const float* res, float* Cf, unsigned short* Cb,
                               int M, int N, int K, int dogelu, int resMask = -1, int Z = 1,
                               long long aBS = 0, long long bBS = 0, long long cBS = 0, long long biasBS = 0) {
    hipLaunchKernelGGL(mgemm_k, dim3(N / 128, M / 256, Z), dim3(256), 0, stream,
                       A, Bt, bias, res, Cf, Cb, N, K, K, dogelu, resMask, aBS, bBS, cBS, biasBS);
}

static inline void gemm_part(hipStream_t stream, const unsigned short* A, const unsigned short* Bt,
                             float* part, int M, int N, int K, int S) {
    int Klen = K / S;
    hipLaunchKernelGGL(mgemm_k, dim3(N / 128, M / 256, S), dim3(256), 0, stream,
                       A, Bt, (const float*)nullptr, (const float*)nullptr, part, (unsigned short*)nullptr,
                       N, K, Klen, 0, -1, (long long)Klen, (long long)Klen, (long long)M * N, 0LL);
}

static inline void gemm_splitk(hipStream_t stream, const unsigned short* A, const unsigned short* Bt,
                               float* part, int M, int N, int K, int S,
                               const float* bias, const float* res, float* Cf, unsigned short* Cb,
                               int dogelu, int resMask = -1) {
    gemm_part(stream, A, Bt, part, M, N, K, S);
    hipLaunchKernelGGL(redep_k, dim3((unsigned)((size_t)M * N / 1024)), dim3(256), 0, stream,
                       part, S, (long long)M * N, bias, res, Cf, Cb, N, dogelu, resMask);
}

static inline void gemm_splitk_ln(hipStream_t stream, const unsigned short* A, const unsigned short* Bt,
                                  float* part, int M, int N, int K, int S,
                                  const float* bias, const float* res, int resMask,
                                  float* hout, unsigned short* ybf,
                                  const float* lns, const float* lnb) {
    gemm_part(stream, A, Bt, part, M, N, K, S);
    hipLaunchKernelGGL(redln_k, dim3(M), dim3(256), 0, stream,
                       part, S, (long long)M * N, bias, res, resMask, hout, ybf, lns, lnb, N);
}

extern "C" void kernel_launch(void* const* d_in, const int* in_sizes, int n_in,
                              void* d_out, int out_size, void* d_ws, size_t ws_size,
                              hipStream_t stream) {
    (void)in_sizes; (void)n_in; (void)out_size; (void)ws_size;
    const float* x          = (const float*)d_in[0];
    const float* mask_rand  = (const float*)d_in[1];
    const float* conv_w     = (const float*)d_in[2];
    const float* conv_b     = (const float*)d_in[3];
    const float* pos_emb    = (const float*)d_in[4];
    const float* enc_ln1_s  = (const float*)d_in[5];
    const float* enc_ln1_b  = (const float*)d_in[6];
    const float* enc_qkv_w  = (const float*)d_in[7];
    const float* enc_proj_w = (const float*)d_in[8];
    const float* enc_proj_b = (const float*)d_in[9];
    const float* enc_ln2_s  = (const float*)d_in[10];
    const float* enc_ln2_b  = (const float*)d_in[11];
    const float* enc_mlp_w1 = (const float*)d_in[12];
    const float* enc_mlp_b1 = (const float*)d_in[13];
    const float* enc_mlp_w2 = (const float*)d_in[14];
    const float* enc_mlp_b2 = (const float*)d_in[15];
    const float* e2d_w      = (const float*)d_in[16];
    const float* e2d_b      = (const float*)d_in[17];
    const float* dec_query  = (const float*)d_in[18];
    const float* dec_ln1_s  = (const float*)d_in[19];
    const float* dec_ln1_b  = (const float*)d_in[20];
    const float* dec_qkv_w  = (const float*)d_in[21];
    const float* dec_qkv_b  = (const float*)d_in[22];
    const float* dec_out_w  = (const float*)d_in[23];
    const float* dec_out_b  = (const float*)d_in[24];
    const float* dec_ln2_s  = (const float*)d_in[25];
    const float* dec_ln2_b  = (const float*)d_in[26];
    const float* dec_mlp_w1 = (const float*)d_in[27];
    const float* dec_mlp_b1 = (const float*)d_in[28];
    const float* dec_mlp_w2 = (const float*)d_in[29];
    const float* dec_mlp_b2 = (const float*)d_in[30];
    const float* head_ln_s  = (const float*)d_in[31];
    const float* head_ln_b  = (const float*)d_in[32];
    const float* head_w     = (const float*)d_in[33];
    const float* head_b     = (const float*)d_in[34];
    float* outp = (float*)d_out;

    // ---- workspace layout (float units) ----
    float* w = (float*)d_ws;
    size_t off = 0;
    int* blockedp = (int*)w; off += 128;
    float* h_buf = w + off; off += (size_t)4096 * 768;
    unsigned short* y_bf = (unsigned short*)(w + off); off += (size_t)4096 * 768 / 2;
    unsigned short* qkv_bf = (unsigned short*)(w + off); off += (size_t)4096 * 2304 / 2;
    unsigned short* mlp_bf = (unsigned short*)(w + off); off += (size_t)4096 * 3072 / 2;
    unsigned short* mem_bf = (unsigned short*)(w + off); off += (size_t)4096 * 512 / 2;
    float* dq_buf = w + off; off += (size_t)1024 * 512;
    unsigned short* R = (unsigned short*)(w + off); off += (size_t)16777216 / 2;  // 33.5 MB region
    unsigned short* decQkvT = (unsigned short*)(w + off); off += (size_t)12 * 262144 / 2;
    unsigned short* decOutT = (unsigned short*)(w + off); off += (size_t)4 * 262144 / 2;
    unsigned short* decMlp1T = (unsigned short*)(w + off); off += (size_t)4 * 1048576 / 2;
    unsigned short* decMlp2T = (unsigned short*)(w + off); off += (size_t)4 * 1048576 / 2;
    unsigned short* e2dT = (unsigned short*)(w + off); off += (size_t)393216 / 2;
    unsigned short* headT = (unsigned short*)(w + off); off += (size_t)393216 / 2;
    float* part_buf = w + off; off += (size_t)4 * 4096 * 768;  // split-K partials

    unsigned short* convW_bf = R;
    unsigned short* wqkvT = R;
    unsigned short* wprojT = R + (size_t)1769472;
    unsigned short* wmlp1T = R + (size_t)2359296;
    unsigned short* wmlp2T = R + (size_t)4718592;
    unsigned short* KdAll = R;
    unsigned short* VdAll = R + (size_t)8388608;

    unsigned short* xf_bf = mlp_bf;
    const float* fnull = nullptr;
    float* f32null = nullptr;
    unsigned short* bfnull = nullptr;
    const float scale = 0.125f;

    // ---- upfront prep ----
    hipLaunchKernelGGL(mask_k, dim3(1), dim3(128), 0, stream, mask_rand, blockedp);
    hipLaunchKernelGGL(wtrans_k, dim3(16, 16, 12), dim3(256), 0, stream, dec_qkv_w, decQkvT, 512, 512);
    hipLaunchKernelGGL(wtrans_k, dim3(16, 16, 4), dim3(256), 0, stream, dec_out_w, decOutT, 512, 512);
    hipLaunchKernelGGL(wtrans_k, dim3(64, 16, 4), dim3(256), 0, stream, dec_mlp_w1, decMlp1T, 512, 2048);
    hipLaunchKernelGGL(wtrans_k, dim3(16, 64, 4), dim3(256), 0, stream, dec_mlp_w2, decMlp2T, 2048, 512);
    hipLaunchKernelGGL(wtrans_k, dim3(16, 24, 1), dim3(256), 0, stream, e2d_w, e2dT, 768, 512);
    hipLaunchKernelGGL(wtrans_k, dim3(24, 16, 1), dim3(256), 0, stream, head_w, headT, 512, 768);
    hipLaunchKernelGGL(cast_k, dim3((768 * 3072 / 4 + 255) / 256), dim3(256), 0, stream,
                       conv_w, convW_bf, 768 * 3072 / 4);
    hipLaunchKernelGGL(gather_k, dim3(12288), dim3(256), 0, stream, x, xf_bf);
    // patchify (split-K 4) + bias + pos_emb + fused LN1(layer 0)
    gemm_splitk_ln(stream, xf_bf, convW_bf, part_buf, 4096, 768, 3072, 4,
                   conv_b, pos_emb, 511, h_buf, y_bf, enc_ln1_s, enc_ln1_b);

    // -------- encoder --------
    for (int l = 0; l < L_; ++l) {
        const int* blk = blockedp + l * 16;
        hipLaunchKernelGGL(wtransenc_k, dim3(6912), dim3(256), 0, stream,
                           enc_qkv_w + (size_t)l * 768 * 2304, enc_proj_w + (size_t)l * 768 * 768,
                           enc_mlp_w1 + (size_t)l * 768 * 3072, enc_mlp_w2 + (size_t)l * 3072 * 768,
                           wqkvT, wprojT, wmlp1T, wmlp2T);
        launch_gemm(stream, y_bf, wqkvT, fnull, fnull, f32null, qkv_bf, 4096, 2304, 768, 0);
        hipLaunchKernelGGL(fattn_k, dim3(B_ * NH_, S_ / 64), dim3(256), 0, stream,
                           qkv_bf, qkv_bf + 768, qkv_bf + 1536, y_bf,
                           2304, 2304, 768, S_, S_, NH_, scale, blk);
        // proj: split-K 2, res=h, fused LN2 -> y_bf
        gemm_splitk_ln(stream, y_bf, wprojT, part_buf, 4096, 768, 768, 2,
                       enc_proj_b + l * 768, h_buf, -1, h_buf, y_bf,
                       enc_ln2_s + l * 768, enc_ln2_b + l * 768);
        launch_gemm(stream, y_bf, wmlp1T, enc_mlp_b1 + l * 3072, fnull, f32null, mlp_bf, 4096, 3072, 768, 1);
        // mlp2: split-K 4, res=h, fused next-LN1 (raw cast on last layer)
        gemm_splitk_ln(stream, mlp_bf, wmlp2T, part_buf, 4096, 768, 3072, 4,
                       enc_mlp_b2 + l * 768, h_buf, -1, h_buf, y_bf,
                       (l < L_ - 1) ? (enc_ln1_s + (l + 1) * 768) : fnull,
                       (l < L_ - 1) ? (enc_ln1_b + (l + 1) * 768) : fnull);
    }

    // -------- enc2dec --------
    gemm_splitk(stream, y_bf, e2dT, part_buf, 4096, 512, 768, 2,
                e2d_b, fnull, f32null, mem_bf, 0);
    hipLaunchKernelGGL(dqinitln_k, dim3(1024), dim3(256), 0, stream,
                       dq_buf, y_bf, dec_query, dec_ln1_s, dec_ln1_b);
    launch_gemm(stream, mem_bf, decQkvT + (size_t)262144, dec_qkv_b + 512, fnull, f32null, KdAll,
                4096, 512, 512, 0, -1, 4, 0, 3LL * 262144, 4096LL * 512, 3LL * 512);
    launch_gemm(stream, mem_bf, decQkvT + (size_t)2 * 262144, dec_qkv_b + 2 * 512, fnull, f32null, VdAll,
                4096, 512, 512, 0, -1, 4, 0, 3LL * 262144, 4096LL * 512, 3LL * 512);

    // -------- decoder --------
    unsigned short* Qd = qkv_bf;
    for (int l = 0; l < LD_; ++l) {
        unsigned short* Kd = KdAll + (size_t)l * 4096 * 512;
        unsigned short* Vd = VdAll + (size_t)l * 4096 * 512;
        gemm_splitk(stream, y_bf, decQkvT + (size_t)(l * 3) * 262144, part_buf, 1024, 512, 512, 4,
                    dec_qkv_b + (l * 3) * 512, fnull, f32null, Qd, 0);
        hipLaunchKernelGGL(fattn_k, dim3(B_ * NHD_, P_ / 64), dim3(256), 0, stream,
                           Qd, Kd, Vd, y_bf, 512, 512, 512, P_, S_, NHD_, scale, (const int*)nullptr);
        // out: split-K 4, res=dq, fused LN2 -> y_bf
        gemm_splitk_ln(stream, y_bf, decOutT + (size_t)l * 262144, part_buf, 1024, 512, 512, 4,
                       dec_out_b + l * 512, dq_buf, -1, dq_buf, y_bf,
                       dec_ln2_s + l * 512, dec_ln2_b + l * 512);
        gemm_splitk(stream, y_bf, decMlp1T + (size_t)l * 1048576, part_buf, 1024, 2048, 512, 2,
                    dec_mlp_b1 + l * 2048, fnull, f32null, mlp_bf, 1);
        // mlp2: split-K 8, res=dq, fused next-LN1 (head_ln on last)
        gemm_splitk_ln(stream, mlp_bf, decMlp2T + (size_t)l * 1048576, part_buf, 1024, 512, 2048, 8,
                       dec_mlp_b2 + l * 512, dq_buf, -1, dq_buf, y_bf,
                       (l < LD_ - 1) ? (dec_ln1_s + (l + 1) * 512) : head_ln_s,
                       (l < LD_ - 1) ? (dec_ln1_b + (l + 1) * 512) : head_ln_b);
    }

    // -------- head --------
    gemm_splitk(stream, y_bf, headT, part_buf, 1024, 768, 512, 4,
                head_b, fnull, outp, bfnull, 0);
}

// Round 12
// 2095.542 us; speedup vs baseline: 1.5814x; 1.2030x over previous
//
#include <hip/hip_runtime.h>
#include <math.h>

// ---------------- dims ----------------
#define B_ 8
#define T_ 4
#define C_ 12
#define H_ 128
#define W_ 256
#define P_ 128
#define S_ 512
#define D_ 768
#define NH_ 12
#define HD_ 64
#define L_ 8
#define MLP_ 3072
#define DD_ 512
#define NHD_ 8
#define LD_ 4
#define MLPD_ 2048
#define OUT_ 768

typedef __bf16 bf16x8 __attribute__((ext_vector_type(8)));
typedef float f32x4 __attribute__((ext_vector_type(4)));

static __device__ __forceinline__ unsigned short f2bf(float f) {
    unsigned int u = __float_as_uint(f);
    unsigned int r = (u + 0x7fffu + ((u >> 16) & 1u)) >> 16;
    return (unsigned short)r;
}

// fast GELU: 0.5x(1+tanh(sqrt(2/pi)(x+0.044715x^3))) == x * sigmoid(1.59576912x + 0.07135482x^3)
static __device__ __forceinline__ float fgelu(float v) {
    float u2 = v * (1.5957691216f + 0.0713548162f * v * v);
    return __fdividef(v, 1.f + __expf(-u2));
}

#define GLDS(gp, lp) __builtin_amdgcn_global_load_lds( \
    (const __attribute__((address_space(1))) void*)(gp), \
    (__attribute__((address_space(3))) void*)(lp), 16, 0, 0)

// ---------------- small utility kernels ----------------

__global__ void mask_k(const float* __restrict__ mr, int* __restrict__ blocked) {
    int i = threadIdx.x; // 128 = L*T*T
    if (i < L_ * T_ * T_) {
        int tk = i & 3, tq = (i >> 2) & 3;
        blocked[i] = (mr[i] < 0.8f && tk > tq) ? 1 : 0;
    }
}

// batched transpose + cast: in (batch, Kd, Nd) fp32 -> out (batch, Nd, Kd) bf16
__global__ __launch_bounds__(256) void wtrans_k(const float* __restrict__ in, unsigned short* __restrict__ out,
                                                int Kd, int Nd) {
    __shared__ float tile[32][33];
    int n0 = blockIdx.x * 32, k0 = blockIdx.y * 32;
    size_t boff = (size_t)blockIdx.z * Kd * Nd;
    const float* src = in + boff;
    unsigned short* dst = out + boff;
    int tx = threadIdx.x & 31, ty = threadIdx.x >> 5; // 32 x 8
#pragma unroll
    for (int i = 0; i < 32; i += 8)
        tile[ty + i][tx] = src[(size_t)(k0 + ty + i) * Nd + n0 + tx];
    __syncthreads();
#pragma unroll
    for (int i = 0; i < 32; i += 8)
        dst[(size_t)(n0 + ty + i) * Kd + k0 + tx] = f2bf(tile[tx][ty + i]);
}

// one encoder layer: transpose all 4 weights in one launch (6912 tile-blocks)
__global__ __launch_bounds__(256) void wtransenc_k(const float* __restrict__ s0, const float* __restrict__ s1,
                                                   const float* __restrict__ s2, const float* __restrict__ s3,
                                                   unsigned short* __restrict__ d0, unsigned short* __restrict__ d1,
                                                   unsigned short* __restrict__ d2, unsigned short* __restrict__ d3) {
    __shared__ float tile[32][33];
    int bid = blockIdx.x;
    const float* src; unsigned short* dst; int Kd, Nd, tt;
    if (bid < 1728)      { src = s0; dst = d0; Kd = 768;  Nd = 2304; tt = bid; }
    else if (bid < 2304) { src = s1; dst = d1; Kd = 768;  Nd = 768;  tt = bid - 1728; }
    else if (bid < 4608) { src = s2; dst = d2; Kd = 768;  Nd = 3072; tt = bid - 2304; }
    else                 { src = s3; dst = d3; Kd = 3072; Nd = 768;  tt = bid - 4608; }
    int nT = Nd >> 5;
    int n0 = (tt % nT) * 32, k0 = (tt / nT) * 32;
    int tx = threadIdx.x & 31, ty = threadIdx.x >> 5;
#pragma unroll
    for (int i = 0; i < 32; i += 8)
        tile[ty + i][tx] = src[(size_t)(k0 + ty + i) * Nd + n0 + tx];
    __syncthreads();
#pragma unroll
    for (int i = 0; i < 32; i += 8)
        dst[(size_t)(n0 + ty + i) * Kd + k0 + tx] = f2bf(tile[tx][ty + i]);
}

// xf[bt, p, c*256+ph*16+pw] = x[bt, c, hp*16+ph, wp*16+pw]  (bf16 out)
__global__ void gather_k(const float* __restrict__ x, unsigned short* __restrict__ xf) {
    size_t i4 = ((size_t)blockIdx.x * 256 + threadIdx.x) * 4;
    if (i4 >= (size_t)4096 * 3072) return;
    int row = (int)(i4 / 3072), col = (int)(i4 % 3072);
    int bt = row >> 7, p = row & 127;
    int hp = p >> 4, wp = p & 15;
    int c = col >> 8, rem = col & 255;
    int ph = rem >> 4, pw0 = rem & 15;
    const float* src = x + (((size_t)(bt * C_ + c) * H_ + hp * 16 + ph) * W_ + wp * 16 + pw0);
    float4 v = *(const float4*)src;
    uint2 o;
    o.x = (unsigned)f2bf(v.x) | ((unsigned)f2bf(v.y) << 16);
    o.y = (unsigned)f2bf(v.z) | ((unsigned)f2bf(v.w) << 16);
    *(uint2*)(xf + i4) = o;
}

// linear cast fp32 -> bf16, n multiple of 4
__global__ void cast_k(const float* __restrict__ in, unsigned short* __restrict__ out, int n4) {
    int i = blockIdx.x * 256 + threadIdx.x;
    if (i >= n4) return;
    float4 v = *(const float4*)(in + (size_t)i * 4);
    uint2 o;
    o.x = (unsigned)f2bf(v.x) | ((unsigned)f2bf(v.y) << 16);
    o.y = (unsigned)f2bf(v.z) | ((unsigned)f2bf(v.w) << 16);
    *(uint2*)(out + (size_t)i * 4) = o;
}

// dq init + fused LN of dec_query rows
__global__ __launch_bounds__(256) void dqinitln_k(float* __restrict__ dq, unsigned short* __restrict__ ybf,
                                                  const float* __restrict__ q0,
                                                  const float* __restrict__ lns, const float* __restrict__ lnb) {
    __shared__ float rs[4], rq[4];
    int row = blockIdx.x, t = threadIdx.x;  // 1024 rows
    int p = row & 127;
    float v0 = q0[p * 512 + t], v1 = q0[p * 512 + t + 256];
    dq[(size_t)row * 512 + t] = v0;
    dq[(size_t)row * 512 + t + 256] = v1;
    float s1 = v0 + v1, s2 = v0 * v0 + v1 * v1;
    for (int o = 32; o; o >>= 1) { s1 += __shfl_xor(s1, o); s2 += __shfl_xor(s2, o); }
    if ((t & 63) == 0) { rs[t >> 6] = s1; rq[t >> 6] = s2; }
    __syncthreads();
    s1 = rs[0] + rs[1] + rs[2] + rs[3];
    s2 = rq[0] + rq[1] + rq[2] + rq[3];
    float mean = s1 / 512.f;
    float inv = rsqrtf(s2 / 512.f - mean * mean + 1e-5f);
    ybf[(size_t)row * 512 + t] = f2bf((v0 - mean) * inv * lns[t] + lnb[t]);
    ybf[(size_t)row * 512 + t + 256] = f2bf((v1 - mean) * inv * lns[t + 256] + lnb[t + 256]);
}

// ---------------- bf16 MFMA GEMM: BK=32, 2-stage, single barrier/step, 32KB LDS ----------------
// (r8 configuration — measured best: mlp1-class 49us, MfmaUtil 14.5%, occ 26%)
__global__ __launch_bounds__(256, 4) void mgemm_k(const unsigned short* __restrict__ A,
                                                  const unsigned short* __restrict__ Bt,
                                                  const float* __restrict__ bias,
                                                  const float* __restrict__ res,
                                                  float* Cf, unsigned short* Cb,
                                                  int N, int Kstride, int Klen, int dogelu, int resMask,
                                                  long long aBS, long long bBS, long long cBS, long long biasBS) {
    __shared__ unsigned short lA[2][128 * 32];
    __shared__ unsigned short lB[2][128 * 32];
    const int t = threadIdx.x, w = t >> 6, ln = t & 63;

    const int z = blockIdx.z;
    A += (size_t)z * aBS;
    Bt += (size_t)z * bBS;
    if (bias) bias += (size_t)z * biasBS;
    if (Cf) Cf += (size_t)z * cBS;
    if (Cb) Cb += (size_t)z * cBS;

    // bijective XCD swizzle (m204)
    int nwg = gridDim.x * gridDim.y;
    int orig = blockIdx.y * gridDim.x + blockIdx.x;
    int qq = nwg >> 3, rr = nwg & 7;
    int xcd = orig & 7, lid = orig >> 3;
    int swz = (xcd < rr) ? (xcd * (qq + 1) + lid) : (rr * (qq + 1) + (xcd - rr) * qq + lid);
    const int row0 = (swz / gridDim.x) * 128, col0 = (swz % gridDim.x) * 128;
    const int wr = w >> 1, wc = w & 1;

    f32x4 acc[4][4] = {};

    const unsigned short* gA[2];
    const unsigned short* gB[2];
    int ldsOff[2];
#pragma unroll
    for (int u = 0; u < 2; ++u) {
        int ch = u * 256 + w * 64 + ln;          // 0..511
        int r2 = ch >> 3, sl = ch & 7;
        int inv = sl ^ (r2 & 7);
        int ra = (r2 << 1) | (inv >> 2), c4 = inv & 3;
        gA[u] = A + (size_t)(row0 + ra) * Kstride + (c4 << 3);
        gB[u] = Bt + (size_t)(col0 + ra) * Kstride + (c4 << 3);
        ldsOff[u] = (u * 256 + w * 64) << 4;
    }
    int offA[4], offB[4];
    {
        int s = ln >> 4;
#pragma unroll
        for (int f = 0; f < 4; ++f) {
            int ra = wr * 64 + f * 16 + (ln & 15);
            offA[f] = (ra >> 1) * 128 + ((((((ra & 1) << 2) | s)) ^ ((ra >> 1) & 7)) << 4);
            int rb = wc * 64 + f * 16 + (ln & 15);
            offB[f] = (rb >> 1) * 128 + ((((((rb & 1) << 2) | s)) ^ ((rb >> 1) & 7)) << 4);
        }
    }

    const int nt = Klen >> 5;
#pragma unroll
    for (int u = 0; u < 2; ++u) GLDS(gA[u], (char*)&lA[0][0] + ldsOff[u]);
#pragma unroll
    for (int u = 0; u < 2; ++u) GLDS(gB[u], (char*)&lB[0][0] + ldsOff[u]);

    for (int tt = 0; tt < nt; ++tt) {
        const int cur = tt & 1;
        asm volatile("s_waitcnt vmcnt(0)" ::: "memory");
        __builtin_amdgcn_s_barrier();
        __builtin_amdgcn_sched_barrier(0);
        if (tt + 1 < nt) {
            const int koff = (tt + 1) << 5;
#pragma unroll
            for (int u = 0; u < 2; ++u) GLDS(gA[u] + koff, (char*)&lA[cur ^ 1][0] + ldsOff[u]);
#pragma unroll
            for (int u = 0; u < 2; ++u) GLDS(gB[u] + koff, (char*)&lB[cur ^ 1][0] + ldsOff[u]);
        }
        bf16x8 av[4], bv[4];
#pragma unroll
        for (int f = 0; f < 4; ++f) {
            av[f] = *(const bf16x8*)((const char*)&lA[cur][0] + offA[f]);
            bv[f] = *(const bf16x8*)((const char*)&lB[cur][0] + offB[f]);
        }
#pragma unroll
        for (int i = 0; i < 4; ++i)
#pragma unroll
            for (int j = 0; j < 4; ++j)
                acc[i][j] = __builtin_amdgcn_mfma_f32_16x16x32_bf16(av[i], bv[j], acc[i][j], 0, 0, 0);
    }

    const int cl = ln & 15, rg = ln >> 4;
#pragma unroll
    for (int i = 0; i < 4; ++i) {
#pragma unroll
        for (int j = 0; j < 4; ++j) {
#pragma unroll
            for (int r = 0; r < 4; ++r) {
                int row = row0 + wr * 64 + i * 16 + rg * 4 + r;
                int col = col0 + wc * 64 + j * 16 + cl;
                float v = acc[i][j][r];
                if (bias) v += bias[col];
                if (dogelu) v = fgelu(v);
                if (res) v += res[(size_t)(row & resMask) * N + col];
                if (Cf) Cf[(size_t)row * N + col] = v;
                if (Cb) Cb[(size_t)row * N + col] = f2bf(v);
            }
        }
    }
}

// ---------------- split-K reduce + epilogue (element-parallel) ----------------
__global__ __launch_bounds__(256) void redep_k(const float* __restrict__ part, int S, long long pstride,
                                               const float* __restrict__ bias, const float* __restrict__ res,
                                               float* __restrict__ Cf, unsigned short* __restrict__ Cb,
                                               int N, int dogelu, int resMask) {
    size_t i4 = ((size_t)blockIdx.x * 256 + threadIdx.x) * 4;
    int row = (int)(i4 / N), col = (int)(i4 % N);
    float4 acc = *(const float4*)(part + i4);
    for (int s = 1; s < S; ++s) {
        float4 p = *(const float4*)(part + (size_t)s * pstride + i4);
        acc.x += p.x; acc.y += p.y; acc.z += p.z; acc.w += p.w;
    }
    if (bias) {
        float4 bv = *(const float4*)(bias + col);
        acc.x += bv.x; acc.y += bv.y; acc.z += bv.z; acc.w += bv.w;
    }
    if (dogelu) {
        acc.x = fgelu(acc.x);
        acc.y = fgelu(acc.y);
        acc.z = fgelu(acc.z);
        acc.w = fgelu(acc.w);
    }
    if (res) {
        float4 rv = *(const float4*)(res + (size_t)(row & resMask) * N + col);
        acc.x += rv.x; acc.y += rv.y; acc.z += rv.z; acc.w += rv.w;
    }
    if (Cf) *(float4*)(Cf + i4) = acc;
    if (Cb) {
        uint2 o;
        o.x = (unsigned)f2bf(acc.x) | ((unsigned)f2bf(acc.y) << 16);
        o.y = (unsigned)f2bf(acc.z) | ((unsigned)f2bf(acc.w) << 16);
        *(uint2*)(Cb + i4) = o;
    }
}

// ---------------- split-K reduce + residual + fused LayerNorm (row per block) ----------------
__global__ __launch_bounds__(256) void redln_k(const float* __restrict__ part, int S, long long pstride,
                                               const float* __restrict__ bias,
                                               const float* __restrict__ res, int resMask,
                                               float* __restrict__ hout, unsigned short* __restrict__ ybf,
                                               const float* __restrict__ lns, const float* __restrict__ lnb,
                                               int N) {
    __shared__ float rs[4], rq[4];
    int row = blockIdx.x, t = threadIdx.x;
    float vbuf[3];
    float s1 = 0.f, s2 = 0.f;
    int nc = 0;
    for (int c = t; c < N; c += 256, ++nc) {
        size_t idx = (size_t)row * N + c;
        float a = part[idx];
        for (int s = 1; s < S; ++s) a += part[(size_t)s * pstride + idx];
        if (bias) a += bias[c];
        if (res) a += res[(size_t)(row & resMask) * N + c];
        if (hout) hout[idx] = a;
        vbuf[nc] = a;
        s1 += a; s2 += a * a;
    }
    if (lns) {
        for (int o = 32; o; o >>= 1) { s1 += __shfl_xor(s1, o); s2 += __shfl_xor(s2, o); }
        if ((t & 63) == 0) { rs[t >> 6] = s1; rq[t >> 6] = s2; }
        __syncthreads();
        s1 = rs[0] + rs[1] + rs[2] + rs[3];
        s2 = rq[0] + rq[1] + rq[2] + rq[3];
        float mean = s1 / N;
        float inv = rsqrtf(s2 / N - mean * mean + 1e-5f);
        nc = 0;
        for (int c = t; c < N; c += 256, ++nc)
            ybf[(size_t)row * N + c] = f2bf((vbuf[nc] - mean) * inv * lns[c] + lnb[c]);
    } else if (ybf) {
        nc = 0;
        for (int c = t; c < N; c += 256, ++nc)
            ybf[(size_t)row * N + c] = f2bf(vbuf[nc]);
    }
}

// ---------------- fused flash attention (bf16 MFMA) ----------------
__global__ __launch_bounds__(256) void fattn_k(
    const unsigned short* __restrict__ Qp, const unsigned short* __restrict__ Kp,
    const unsigned short* __restrict__ Vp, unsigned short* __restrict__ Op,
    int q_rstride, int kv_rstride, int o_rstride, int Sq, int Sk, int nh,
    float scale, const int* __restrict__ blk) {
    __shared__ unsigned short lK[64 * 64];
    __shared__ unsigned short lV[64 * 64];
    __shared__ unsigned short lP[4][16 * 64];
    const int t = threadIdx.x, wv = t >> 6, ln = t & 63;
    const int bh = blockIdx.x, b = bh / nh, hh = bh % nh;
    const int q0 = blockIdx.y * 64;
    const int tq = q0 >> 7;
    const int cl = ln & 15, rg = ln >> 4;

    bf16x8 qa[2];
    {
        const unsigned short* qrow = Qp + (size_t)(b * Sq + q0 + wv * 16 + cl) * q_rstride + hh * 64 + rg * 8;
        qa[0] = *(const bf16x8*)(qrow);
        qa[1] = *(const bf16x8*)(qrow + 32);
    }
    f32x4 oacc[4] = {};
    float mrow[4] = {-1e30f, -1e30f, -1e30f, -1e30f};
    float lrow[4] = {0.f, 0.f, 0.f, 0.f};

    int krr[2], kcc[2];
#pragma unroll
    for (int u = 0; u < 2; ++u) {
        int ch = u * 256 + t;
        krr[u] = ch >> 3;
        kcc[u] = ((ch & 7) ^ (krr[u] & 7)) << 3;
    }
    const int vk0 = (t >> 4) * 4, vd0 = (t & 15) * 4;

    for (int kc = 0; kc < Sk; kc += 64) {
        if (blk && blk[tq * 4 + (kc >> 7)]) continue;
        __syncthreads();
#pragma unroll
        for (int u = 0; u < 2; ++u)
            GLDS(Kp + (size_t)(b * Sk + kc + krr[u]) * kv_rstride + hh * 64 + kcc[u],
                 (char*)lK + ((u * 256 + wv * 64) << 4));
        {
            unsigned short a0[4], a1[4], a2[4], a3[4];
            const unsigned short* s0 = Vp + (size_t)(b * Sk + kc + vk0 + 0) * kv_rstride + hh * 64 + vd0;
            const unsigned short* s1 = Vp + (size_t)(b * Sk + kc + vk0 + 1) * kv_rstride + hh * 64 + vd0;
            const unsigned short* s2 = Vp + (size_t)(b * Sk + kc + vk0 + 2) * kv_rstride + hh * 64 + vd0;
            const unsigned short* s3 = Vp + (size_t)(b * Sk + kc + vk0 + 3) * kv_rstride + hh * 64 + vd0;
            *(uint2*)a0 = *(const uint2*)s0;
            *(uint2*)a1 = *(const uint2*)s1;
            *(uint2*)a2 = *(const uint2*)s2;
            *(uint2*)a3 = *(const uint2*)s3;
#pragma unroll
            for (int j = 0; j < 4; ++j) {
                int d = vd0 + j;
                int slot = (vk0 >> 3) ^ ((d + (d >> 3)) & 7);
                unsigned short pk[4] = {a0[j], a1[j], a2[j], a3[j]};
                *(uint2*)&lV[d * 64 + (slot << 3) + (vk0 & 7)] = *(uint2*)pk;
            }
        }
        __syncthreads();

        f32x4 sacc[4] = {};
#pragma unroll
        for (int kk = 0; kk < 2; ++kk)
#pragma unroll
            for (int f = 0; f < 4; ++f) {
                int rk = f * 16 + cl;
                bf16x8 kb = *(const bf16x8*)&lK[rk * 64 + (((kk * 4 + rg) ^ (rk & 7)) << 3)];
                sacc[f] = __builtin_amdgcn_mfma_f32_16x16x32_bf16(qa[kk], kb, sacc[f], 0, 0, 0);
            }
        float cm[4] = {-1e30f, -1e30f, -1e30f, -1e30f};
#pragma unroll
        for (int f = 0; f < 4; ++f)
#pragma unroll
            for (int r = 0; r < 4; ++r) {
                float v = sacc[f][r] * scale;
                sacc[f][r] = v;
                cm[r] = fmaxf(cm[r], v);
            }
#pragma unroll
        for (int o = 8; o; o >>= 1)
#pragma unroll
            for (int r = 0; r < 4; ++r) cm[r] = fmaxf(cm[r], __shfl_xor(cm[r], o));
        float corr[4], rsum[4];
#pragma unroll
        for (int r = 0; r < 4; ++r) {
            float nm = fmaxf(mrow[r], cm[r]);
            corr[r] = __expf(mrow[r] - nm);
            mrow[r] = nm;
            rsum[r] = 0.f;
        }
#pragma unroll
        for (int f = 0; f < 4; ++f)
#pragma unroll
            for (int r = 0; r < 4; ++r) {
                float p = __expf(sacc[f][r] - mrow[r]);
                sacc[f][r] = p;
                rsum[r] += p;
            }
#pragma unroll
        for (int o = 8; o; o >>= 1)
#pragma unroll
            for (int r = 0; r < 4; ++r) rsum[r] += __shfl_xor(rsum[r], o);
#pragma unroll
        for (int r = 0; r < 4; ++r) lrow[r] = lrow[r] * corr[r] + rsum[r];
#pragma unroll
        for (int f = 0; f < 4; ++f)
#pragma unroll
            for (int r = 0; r < 4; ++r) oacc[f][r] *= corr[r];
#pragma unroll
        for (int f = 0; f < 4; ++f)
#pragma unroll
            for (int r = 0; r < 4; ++r) {
                int q = rg * 4 + r, key = f * 16 + cl;
                lP[wv][q * 64 + (((key >> 3) ^ (q & 7)) << 3) + (key & 7)] = f2bf(sacc[f][r]);
            }
#pragma unroll
        for (int kk = 0; kk < 2; ++kk) {
            bf16x8 pa = *(const bf16x8*)&lP[wv][cl * 64 + (((kk * 4 + rg) ^ (cl & 7)) << 3)];
#pragma unroll
            for (int f = 0; f < 4; ++f) {
                int d = f * 16 + cl;
                bf16x8 vb = *(const bf16x8*)&lV[d * 64 + (((kk * 4 + rg) ^ ((d + (d >> 3)) & 7)) << 3)];
                oacc[f] = __builtin_amdgcn_mfma_f32_16x16x32_bf16(pa, vb, oacc[f], 0, 0, 0);
            }
        }
    }

    float inv[4];
#pragma unroll
    for (int r = 0; r < 4; ++r) inv[r] = 1.f / lrow[r];
#pragma unroll
    for (int f = 0; f < 4; ++f)
#pragma unroll
        for (int r = 0; r < 4; ++r) {
            int q = q0 + wv * 16 + rg * 4 + r;
            int d = f * 16 + cl;
            Op[(size_t)(b * Sq + q) * o_rstride + hh * 64 + d] = f2bf(oacc[f][r] * inv[r]);
        }
}

// ---------------- host helpers ----------------
static inline void launch_gemm(hipStream_t stream, const unsigned short* A, const unsigned short* Bt,
                               const float* bias, const float* res, float* Cf, unsigned short* Cb,
                               int M, int N, int K, int dogelu, int resMask = -1, int Z = 1,
                               long long aBS = 0, long long bBS = 0, long long cBS = 0, long long biasBS = 0) {
    hipLaunchKernelGGL(mgemm_k, dim3(N / 128, M / 128, Z), dim3(256), 0, stream,
                       A, Bt, bias, res, Cf, Cb, N, K, K, dogelu, resMask, aBS, bBS, cBS, biasBS);
}

static inline void gemm_part(hipStream_t stream, const unsigned short* A, const unsigned short* Bt,
                             float* part, int M, int N, int K, int S) {
    int Klen = K / S;
    hipLaunchKernelGGL(mgemm_k, dim3(N / 128, M / 128, S), dim3(256), 0, stream,
                       A, Bt, (const float*)nullptr, (const float*)nullptr, part, (unsigned short*)nullptr,
                       N, K, Klen, 0, -1, (long long)Klen, (long long)Klen, (long long)M * N, 0LL);
}

static inline void gemm_splitk(hipStream_t stream, const unsigned short* A, const unsigned short* Bt,
                               float* part, int M, int N, int K, int S,
                               const float* bias, const float* res, float* Cf, unsigned short* Cb,
                               int dogelu, int resMask = -1) {
    gemm_part(stream, A, Bt, part, M, N, K, S);
    hipLaunchKernelGGL(redep_k, dim3((unsigned)((size_t)M * N / 1024)), dim3(256), 0, stream,
                       part, S, (long long)M * N, bias, res, Cf, Cb, N, dogelu, resMask);
}

static inline void gemm_splitk_ln(hipStream_t stream, const unsigned short* A, const unsigned short* Bt,
                                  float* part, int M, int N, int K, int S,
                                  const float* bias, const float* res, int resMask,
                                  float* hout, unsigned short* ybf,
                                  const float* lns, const float* lnb) {
    gemm_part(stream, A, Bt, part, M, N, K, S);
    hipLaunchKernelGGL(redln_k, dim3(M), dim3(256), 0, stream,
                       part, S, (long long)M * N, bias, res, resMask, hout, ybf, lns, lnb, N);
}

extern "C" void kernel_launch(void* const* d_in, const int* in_sizes, int n_in,
                              void* d_out, int out_size, void* d_ws, size_t ws_size,
                              hipStream_t stream) {
    (void)in_sizes; (void)n_in; (void)out_size; (void)ws_size;
    const float* x          = (const float*)d_in[0];
    const float* mask_rand  = (const float*)d_in[1];
    const float* conv_w     = (const float*)d_in[2];
    const float* conv_b     = (const float*)d_in[3];
    const float* pos_emb    = (const float*)d_in[4];
    const float* enc_ln1_s  = (const float*)d_in[5];
    const float* enc_ln1_b  = (const float*)d_in[6];
    const float* enc_qkv_w  = (const float*)d_in[7];
    const float* enc_proj_w = (const float*)d_in[8];
    const float* enc_proj_b = (const float*)d_in[9];
    const float* enc_ln2_s  = (const float*)d_in[10];
    const float* enc_ln2_b  = (const float*)d_in[11];
    const float* enc_mlp_w1 = (const float*)d_in[12];
    const float* enc_mlp_b1 = (const float*)d_in[13];
    const float* enc_mlp_w2 = (const float*)d_in[14];
    const float* enc_mlp_b2 = (const float*)d_in[15];
    const float* e2d_w      = (const float*)d_in[16];
    const float* e2d_b      = (const float*)d_in[17];
    const float* dec_query  = (const float*)d_in[18];
    const float* dec_ln1_s  = (const float*)d_in[19];
    const float* dec_ln1_b  = (const float*)d_in[20];
    const float* dec_qkv_w  = (const float*)d_in[21];
    const float* dec_qkv_b  = (const float*)d_in[22];
    const float* dec_out_w  = (const float*)d_in[23];
    const float* dec_out_b  = (const float*)d_in[24];
    const float* dec_ln2_s  = (const float*)d_in[25];
    const float* dec_ln2_b  = (const float*)d_in[26];
    const float* dec_mlp_w1 = (const float*)d_in[27];
    const float* dec_mlp_b1 = (const float*)d_in[28];
    const float* dec_mlp_w2 = (const float*)d_in[29];
    const float* dec_mlp_b2 = (const float*)d_in[30];
    const float* head_ln_s  = (const float*)d_in[31];
    const float* head_ln_b  = (const float*)d_in[32];
    const float* head_w     = (const float*)d_in[33];
    const float* head_b     = (const float*)d_in[34];
    float* outp = (float*)d_out;

    // ---- workspace layout (float units) ----
    float* w = (float*)d_ws;
    size_t off = 0;
    int* blockedp = (int*)w; off += 128;
    float* h_buf = w + off; off += (size_t)4096 * 768;
    unsigned short* y_bf = (unsigned short*)(w + off); off += (size_t)4096 * 768 / 2;
    unsigned short* qkv_bf = (unsigned short*)(w + off); off += (size_t)4096 * 2304 / 2;
    unsigned short* mlp_bf = (unsigned short*)(w + off); off += (size_t)4096 * 3072 / 2;
    unsigned short* mem_bf = (unsigned short*)(w + off); off += (size_t)4096 * 512 / 2;
    float* dq_buf = w + off; off += (size_t)1024 * 512;
    unsigned short* R = (unsigned short*)(w + off); off += (size_t)16777216 / 2;  // 33.5 MB region
    unsigned short* decQkvT = (unsigned short*)(w + off); off += (size_t)12 * 262144 / 2;
    unsigned short* decOutT = (unsigned short*)(w + off); off += (size_t)4 * 262144 / 2;
    unsigned short* decMlp1T = (unsigned short*)(w + off); off += (size_t)4 * 1048576 / 2;
    unsigned short* decMlp2T = (unsigned short*)(w + off); off += (size_t)4 * 1048576 / 2;
    unsigned short* e2dT = (unsigned short*)(w + off); off += (size_t)393216 / 2;
    unsigned short* headT = (unsigned short*)(w + off); off += (size_t)393216 / 2;
    float* part_buf = w + off; off += (size_t)4 * 4096 * 768;  // split-K partials

    unsigned short* convW_bf = R;
    unsigned short* wqkvT = R;
    unsigned short* wprojT = R + (size_t)1769472;
    unsigned short* wmlp1T = R + (size_t)2359296;
    unsigned short* wmlp2T = R + (size_t)4718592;
    unsigned short* KdAll = R;
    unsigned short* VdAll = R + (size_t)8388608;

    unsigned short* xf_bf = mlp_bf;
    const float* fnull = nullptr;
    float* f32null = nullptr;
    unsigned short* bfnull = nullptr;
    const float scale = 0.125f;

    // ---- upfront prep ----
    hipLaunchKernelGGL(mask_k, dim3(1), dim3(128), 0, stream, mask_rand, blockedp);
    hipLaunchKernelGGL(wtrans_k, dim3(16, 16, 12), dim3(256), 0, stream, dec_qkv_w, decQkvT, 512, 512);
    hipLaunchKernelGGL(wtrans_k, dim3(16, 16, 4), dim3(256), 0, stream, dec_out_w, decOutT, 512, 512);
    hipLaunchKernelGGL(wtrans_k, dim3(64, 16, 4), dim3(256), 0, stream, dec_mlp_w1, decMlp1T, 512, 2048);
    hipLaunchKernelGGL(wtrans_k, dim3(16, 64, 4), dim3(256), 0, stream, dec_mlp_w2, decMlp2T, 2048, 512);
    hipLaunchKernelGGL(wtrans_k, dim3(16, 24, 1), dim3(256), 0, stream, e2d_w, e2dT, 768, 512);
    hipLaunchKernelGGL(wtrans_k, dim3(24, 16, 1), dim3(256), 0, stream, head_w, headT, 512, 768);
    hipLaunchKernelGGL(cast_k, dim3((768 * 3072 / 4 + 255) / 256), dim3(256), 0, stream,
                       conv_w, convW_bf, 768 * 3072 / 4);
    hipLaunchKernelGGL(gather_k, dim3(12288), dim3(256), 0, stream, x, xf_bf);
    // patchify (split-K 4) + bias + pos_emb + fused LN1(layer 0)
    gemm_splitk_ln(stream, xf_bf, convW_bf, part_buf, 4096, 768, 3072, 4,
                   conv_b, pos_emb, 511, h_buf, y_bf, enc_ln1_s, enc_ln1_b);

    // -------- encoder --------
    for (int l = 0; l < L_; ++l) {
        const int* blk = blockedp + l * 16;
        hipLaunchKernelGGL(wtransenc_k, dim3(6912), dim3(256), 0, stream,
                           enc_qkv_w + (size_t)l * 768 * 2304, enc_proj_w + (size_t)l * 768 * 768,
                           enc_mlp_w1 + (size_t)l * 768 * 3072, enc_mlp_w2 + (size_t)l * 3072 * 768,
                           wqkvT, wprojT, wmlp1T, wmlp2T);
        launch_gemm(stream, y_bf, wqkvT, fnull, fnull, f32null, qkv_bf, 4096, 2304, 768, 0);
        hipLaunchKernelGGL(fattn_k, dim3(B_ * NH_, S_ / 64), dim3(256), 0, stream,
                           qkv_bf, qkv_bf + 768, qkv_bf + 1536, y_bf,
                           2304, 2304, 768, S_, S_, NH_, scale, blk);
        // proj: split-K 2, res=h, fused LN2 -> y_bf
        gemm_splitk_ln(stream, y_bf, wprojT, part_buf, 4096, 768, 768, 2,
                       enc_proj_b + l * 768, h_buf, -1, h_buf, y_bf,
                       enc_ln2_s + l * 768, enc_ln2_b + l * 768);
        launch_gemm(stream, y_bf, wmlp1T, enc_mlp_b1 + l * 3072, fnull, f32null, mlp_bf, 4096, 3072, 768, 1);
        // mlp2: split-K 4, res=h, fused next-LN1 (raw cast on last layer)
        gemm_splitk_ln(stream, mlp_bf, wmlp2T, part_buf, 4096, 768, 3072, 4,
                       enc_mlp_b2 + l * 768, h_buf, -1, h_buf, y_bf,
                       (l < L_ - 1) ? (enc_ln1_s + (l + 1) * 768) : fnull,
                       (l < L_ - 1) ? (enc_ln1_b + (l + 1) * 768) : fnull);
    }

    // -------- enc2dec --------
    gemm_splitk(stream, y_bf, e2dT, part_buf, 4096, 512, 768, 2,
                e2d_b, fnull, f32null, mem_bf, 0);
    hipLaunchKernelGGL(dqinitln_k, dim3(1024), dim3(256), 0, stream,
                       dq_buf, y_bf, dec_query, dec_ln1_s, dec_ln1_b);
    launch_gemm(stream, mem_bf, decQkvT + (size_t)262144, dec_qkv_b + 512, fnull, f32null, KdAll,
                4096, 512, 512, 0, -1, 4, 0, 3LL * 262144, 4096LL * 512, 3LL * 512);
    launch_gemm(stream, mem_bf, decQkvT + (size_t)2 * 262144, dec_qkv_b + 2 * 512, fnull, f32null, VdAll,
                4096, 512, 512, 0, -1, 4, 0, 3LL * 262144, 4096LL * 512, 3LL * 512);

    // -------- decoder --------
    unsigned short* Qd = qkv_bf;
    for (int l = 0; l < LD_; ++l) {
        unsigned short* Kd = KdAll + (size_t)l * 4096 * 512;
        unsigned short* Vd = VdAll + (size_t)l * 4096 * 512;
        gemm_splitk(stream, y_bf, decQkvT + (size_t)(l * 3) * 262144, part_buf, 1024, 512, 512, 4,
                    dec_qkv_b + (l * 3) * 512, fnull, f32null, Qd, 0);
        hipLaunchKernelGGL(fattn_k, dim3(B_ * NHD_, P_ / 64), dim3(256), 0, stream,
                           Qd, Kd, Vd, y_bf, 512, 512, 512, P_, S_, NHD_, scale, (const int*)nullptr);
        // out: split-K 4, res=dq, fused LN2 -> y_bf
        gemm_splitk_ln(stream, y_bf, decOutT + (size_t)l * 262144, part_buf, 1024, 512, 512, 4,
                       dec_out_b + l * 512, dq_buf, -1, dq_buf, y_bf,
                       dec_ln2_s + l * 512, dec_ln2_b + l * 512);
        gemm_splitk(stream, y_bf, decMlp1T + (size_t)l * 1048576, part_buf, 1024, 2048, 512, 2,
                    dec_mlp_b1 + l * 2048, fnull, f32null, mlp_bf, 1);
        // mlp2: split-K 8, res=dq, fused next-LN1 (head_ln on last)
        gemm_splitk_ln(stream, mlp_bf, decMlp2T + (size_t)l * 1048576, part_buf, 1024, 512, 2048, 8,
                       dec_mlp_b2 + l * 512, dq_buf, -1, dq_buf, y_bf,
                       (l < LD_ - 1) ? (dec_ln1_s + (l + 1) * 512) : head_ln_s,
                       (l < LD_ - 1) ? (dec_ln1_b + (l + 1) * 512) : head_ln_b);
    }

    // -------- head --------
    gemm_splitk(stream, y_bf, headT, part_buf, 1024, 768, 512, 4,
                head_b, fnull, outp, bfnull, 0);
}

// Round 13
// 1990.306 us; speedup vs baseline: 1.6650x; 1.0529x over previous
//
#include <hip/hip_runtime.h>
#include <math.h>

// ---------------- dims ----------------
#define B_ 8
#define T_ 4
#define C_ 12
#define H_ 128
#define W_ 256
#define P_ 128
#define S_ 512
#define D_ 768
#define NH_ 12
#define HD_ 64
#define L_ 8
#define MLP_ 3072
#define DD_ 512
#define NHD_ 8
#define LD_ 4
#define MLPD_ 2048
#define OUT_ 768

typedef __bf16 bf16x8 __attribute__((ext_vector_type(8)));
typedef float f32x4 __attribute__((ext_vector_type(4)));

static __device__ __forceinline__ unsigned short f2bf(float f) {
    unsigned int u = __float_as_uint(f);
    unsigned int r = (u + 0x7fffu + ((u >> 16) & 1u)) >> 16;
    return (unsigned short)r;
}

// fast GELU: 0.5x(1+tanh(sqrt(2/pi)(x+0.044715x^3))) == x * sigmoid(1.59576912x + 0.07135482x^3)
static __device__ __forceinline__ float fgelu(float v) {
    float u2 = v * (1.5957691216f + 0.0713548162f * v * v);
    return __fdividef(v, 1.f + __expf(-u2));
}

#define GLDS(gp, lp) __builtin_amdgcn_global_load_lds( \
    (const __attribute__((address_space(1))) void*)(gp), \
    (__attribute__((address_space(3))) void*)(lp), 16, 0, 0)

// ---------------- small utility kernels ----------------

__global__ void mask_k(const float* __restrict__ mr, int* __restrict__ blocked) {
    int i = threadIdx.x; // 128 = L*T*T
    if (i < L_ * T_ * T_) {
        int tk = i & 3, tq = (i >> 2) & 3;
        blocked[i] = (mr[i] < 0.8f && tk > tq) ? 1 : 0;
    }
}

// batched transpose + cast: in (batch, Kd, Nd) fp32 -> out (batch, Nd, Kd) bf16
__global__ __launch_bounds__(256) void wtrans_k(const float* __restrict__ in, unsigned short* __restrict__ out,
                                                int Kd, int Nd) {
    __shared__ float tile[32][33];
    int n0 = blockIdx.x * 32, k0 = blockIdx.y * 32;
    size_t boff = (size_t)blockIdx.z * Kd * Nd;
    const float* src = in + boff;
    unsigned short* dst = out + boff;
    int tx = threadIdx.x & 31, ty = threadIdx.x >> 5; // 32 x 8
#pragma unroll
    for (int i = 0; i < 32; i += 8)
        tile[ty + i][tx] = src[(size_t)(k0 + ty + i) * Nd + n0 + tx];
    __syncthreads();
#pragma unroll
    for (int i = 0; i < 32; i += 8)
        dst[(size_t)(n0 + ty + i) * Kd + k0 + tx] = f2bf(tile[tx][ty + i]);
}

// one encoder layer: transpose all 4 weights in one launch (6912 tile-blocks)
__global__ __launch_bounds__(256) void wtransenc_k(const float* __restrict__ s0, const float* __restrict__ s1,
                                                   const float* __restrict__ s2, const float* __restrict__ s3,
                                                   unsigned short* __restrict__ d0, unsigned short* __restrict__ d1,
                                                   unsigned short* __restrict__ d2, unsigned short* __restrict__ d3) {
    __shared__ float tile[32][33];
    int bid = blockIdx.x;
    const float* src; unsigned short* dst; int Kd, Nd, tt;
    if (bid < 1728)      { src = s0; dst = d0; Kd = 768;  Nd = 2304; tt = bid; }
    else if (bid < 2304) { src = s1; dst = d1; Kd = 768;  Nd = 768;  tt = bid - 1728; }
    else if (bid < 4608) { src = s2; dst = d2; Kd = 768;  Nd = 3072; tt = bid - 2304; }
    else                 { src = s3; dst = d3; Kd = 3072; Nd = 768;  tt = bid - 4608; }
    int nT = Nd >> 5;
    int n0 = (tt % nT) * 32, k0 = (tt / nT) * 32;
    int tx = threadIdx.x & 31, ty = threadIdx.x >> 5;
#pragma unroll
    for (int i = 0; i < 32; i += 8)
        tile[ty + i][tx] = src[(size_t)(k0 + ty + i) * Nd + n0 + tx];
    __syncthreads();
#pragma unroll
    for (int i = 0; i < 32; i += 8)
        dst[(size_t)(n0 + ty + i) * Kd + k0 + tx] = f2bf(tile[tx][ty + i]);
}

// xf[bt, p, c*256+ph*16+pw] = x[bt, c, hp*16+ph, wp*16+pw]  (bf16 out)
__global__ void gather_k(const float* __restrict__ x, unsigned short* __restrict__ xf) {
    size_t i4 = ((size_t)blockIdx.x * 256 + threadIdx.x) * 4;
    if (i4 >= (size_t)4096 * 3072) return;
    int row = (int)(i4 / 3072), col = (int)(i4 % 3072);
    int bt = row >> 7, p = row & 127;
    int hp = p >> 4, wp = p & 15;
    int c = col >> 8, rem = col & 255;
    int ph = rem >> 4, pw0 = rem & 15;
    const float* src = x + (((size_t)(bt * C_ + c) * H_ + hp * 16 + ph) * W_ + wp * 16 + pw0);
    float4 v = *(const float4*)src;
    uint2 o;
    o.x = (unsigned)f2bf(v.x) | ((unsigned)f2bf(v.y) << 16);
    o.y = (unsigned)f2bf(v.z) | ((unsigned)f2bf(v.w) << 16);
    *(uint2*)(xf + i4) = o;
}

// linear cast fp32 -> bf16, n multiple of 4
__global__ void cast_k(const float* __restrict__ in, unsigned short* __restrict__ out, int n4) {
    int i = blockIdx.x * 256 + threadIdx.x;
    if (i >= n4) return;
    float4 v = *(const float4*)(in + (size_t)i * 4);
    uint2 o;
    o.x = (unsigned)f2bf(v.x) | ((unsigned)f2bf(v.y) << 16);
    o.y = (unsigned)f2bf(v.z) | ((unsigned)f2bf(v.w) << 16);
    *(uint2*)(out + (size_t)i * 4) = o;
}

// dq init + fused LN of dec_query rows
__global__ __launch_bounds__(256) void dqinitln_k(float* __restrict__ dq, unsigned short* __restrict__ ybf,
                                                  const float* __restrict__ q0,
                                                  const float* __restrict__ lns, const float* __restrict__ lnb) {
    __shared__ float rs[4], rq[4];
    int row = blockIdx.x, t = threadIdx.x;  // 1024 rows
    int p = row & 127;
    float v0 = q0[p * 512 + t], v1 = q0[p * 512 + t + 256];
    dq[(size_t)row * 512 + t] = v0;
    dq[(size_t)row * 512 + t + 256] = v1;
    float s1 = v0 + v1, s2 = v0 * v0 + v1 * v1;
    for (int o = 32; o; o >>= 1) { s1 += __shfl_xor(s1, o); s2 += __shfl_xor(s2, o); }
    if ((t & 63) == 0) { rs[t >> 6] = s1; rq[t >> 6] = s2; }
    __syncthreads();
    s1 = rs[0] + rs[1] + rs[2] + rs[3];
    s2 = rq[0] + rq[1] + rq[2] + rq[3];
    float mean = s1 / 512.f;
    float inv = rsqrtf(s2 / 512.f - mean * mean + 1e-5f);
    ybf[(size_t)row * 512 + t] = f2bf((v0 - mean) * inv * lns[t] + lnb[t]);
    ybf[(size_t)row * 512 + t + 256] = f2bf((v1 - mean) * inv * lns[t + 256] + lnb[t + 256]);
}

// ---------------- bf16 MFMA GEMM: BK=32, 2-stage, single barrier/step, 32KB LDS ----------------
// r8 structure + SWAPPED MFMA operands: acc[i][j] = mfma(bv[j], av[i], .) so each lane
// holds 4 CONSECUTIVE COLUMNS at a fixed row -> vectorized float4/uint2 epilogue stores.
__global__ __launch_bounds__(256, 4) void mgemm_k(const unsigned short* __restrict__ A,
                                                  const unsigned short* __restrict__ Bt,
                                                  const float* __restrict__ bias,
                                                  const float* __restrict__ res,
                                                  float* Cf, unsigned short* Cb,
                                                  int N, int Kstride, int Klen, int dogelu, int resMask,
                                                  long long aBS, long long bBS, long long cBS, long long biasBS) {
    __shared__ unsigned short lA[2][128 * 32];
    __shared__ unsigned short lB[2][128 * 32];
    const int t = threadIdx.x, w = t >> 6, ln = t & 63;

    const int z = blockIdx.z;
    A += (size_t)z * aBS;
    Bt += (size_t)z * bBS;
    if (bias) bias += (size_t)z * biasBS;
    if (Cf) Cf += (size_t)z * cBS;
    if (Cb) Cb += (size_t)z * cBS;

    // bijective XCD swizzle (m204)
    int nwg = gridDim.x * gridDim.y;
    int orig = blockIdx.y * gridDim.x + blockIdx.x;
    int qq = nwg >> 3, rr = nwg & 7;
    int xcd = orig & 7, lid = orig >> 3;
    int swz = (xcd < rr) ? (xcd * (qq + 1) + lid) : (rr * (qq + 1) + (xcd - rr) * qq + lid);
    const int row0 = (swz / gridDim.x) * 128, col0 = (swz % gridDim.x) * 128;
    const int wr = w >> 1, wc = w & 1;

    f32x4 acc[4][4] = {};

    const unsigned short* gA[2];
    const unsigned short* gB[2];
    int ldsOff[2];
#pragma unroll
    for (int u = 0; u < 2; ++u) {
        int ch = u * 256 + w * 64 + ln;          // 0..511
        int r2 = ch >> 3, sl = ch & 7;
        int inv = sl ^ (r2 & 7);
        int ra = (r2 << 1) | (inv >> 2), c4 = inv & 3;
        gA[u] = A + (size_t)(row0 + ra) * Kstride + (c4 << 3);
        gB[u] = Bt + (size_t)(col0 + ra) * Kstride + (c4 << 3);
        ldsOff[u] = (u * 256 + w * 64) << 4;
    }
    int offA[4], offB[4];
    {
        int s = ln >> 4;
#pragma unroll
        for (int f = 0; f < 4; ++f) {
            int ra = wr * 64 + f * 16 + (ln & 15);
            offA[f] = (ra >> 1) * 128 + ((((((ra & 1) << 2) | s)) ^ ((ra >> 1) & 7)) << 4);
            int rb = wc * 64 + f * 16 + (ln & 15);
            offB[f] = (rb >> 1) * 128 + ((((((rb & 1) << 2) | s)) ^ ((rb >> 1) & 7)) << 4);
        }
    }

    const int nt = Klen >> 5;
#pragma unroll
    for (int u = 0; u < 2; ++u) GLDS(gA[u], (char*)&lA[0][0] + ldsOff[u]);
#pragma unroll
    for (int u = 0; u < 2; ++u) GLDS(gB[u], (char*)&lB[0][0] + ldsOff[u]);

    for (int tt = 0; tt < nt; ++tt) {
        const int cur = tt & 1;
        asm volatile("s_waitcnt vmcnt(0)" ::: "memory");
        __builtin_amdgcn_s_barrier();
        __builtin_amdgcn_sched_barrier(0);
        if (tt + 1 < nt) {
            const int koff = (tt + 1) << 5;
#pragma unroll
            for (int u = 0; u < 2; ++u) GLDS(gA[u] + koff, (char*)&lA[cur ^ 1][0] + ldsOff[u]);
#pragma unroll
            for (int u = 0; u < 2; ++u) GLDS(gB[u] + koff, (char*)&lB[cur ^ 1][0] + ldsOff[u]);
        }
        bf16x8 av[4], bv[4];
#pragma unroll
        for (int f = 0; f < 4; ++f) {
            av[f] = *(const bf16x8*)((const char*)&lA[cur][0] + offA[f]);
            bv[f] = *(const bf16x8*)((const char*)&lB[cur][0] + offB[f]);
        }
        // swapped operands: lane's 4 acc elems = 4 consecutive N-columns at one M-row
#pragma unroll
        for (int i = 0; i < 4; ++i)
#pragma unroll
            for (int j = 0; j < 4; ++j)
                acc[i][j] = __builtin_amdgcn_mfma_f32_16x16x32_bf16(bv[j], av[i], acc[i][j], 0, 0, 0);
    }

    // epilogue: D layout (swapped): M-row = lane&15 (within frag i), N-col = (lane>>4)*4 + r (within frag j)
    const int cl = ln & 15, rg = ln >> 4;
#pragma unroll
    for (int i = 0; i < 4; ++i) {
        const int row = row0 + wr * 64 + i * 16 + cl;
        const size_t rowN = (size_t)row * N;
        const size_t resRowN = (size_t)(row & resMask) * N;
#pragma unroll
        for (int j = 0; j < 4; ++j) {
            const int c0 = col0 + wc * 64 + j * 16 + rg * 4;
            f32x4 v = acc[i][j];
            if (bias) {
                float4 bv4 = *(const float4*)(bias + c0);
                v[0] += bv4.x; v[1] += bv4.y; v[2] += bv4.z; v[3] += bv4.w;
            }
            if (dogelu) {
                v[0] = fgelu(v[0]); v[1] = fgelu(v[1]); v[2] = fgelu(v[2]); v[3] = fgelu(v[3]);
            }
            if (res) {
                float4 rv = *(const float4*)(res + resRowN + c0);
                v[0] += rv.x; v[1] += rv.y; v[2] += rv.z; v[3] += rv.w;
            }
            if (Cf) *(float4*)(Cf + rowN + c0) = *(float4*)&v;
            if (Cb) {
                uint2 o;
                o.x = (unsigned)f2bf(v[0]) | ((unsigned)f2bf(v[1]) << 16);
                o.y = (unsigned)f2bf(v[2]) | ((unsigned)f2bf(v[3]) << 16);
                *(uint2*)(Cb + rowN + c0) = o;
            }
        }
    }
}

// ---------------- split-K reduce + epilogue (element-parallel) ----------------
__global__ __launch_bounds__(256) void redep_k(const float* __restrict__ part, int S, long long pstride,
                                               const float* __restrict__ bias, const float* __restrict__ res,
                                               float* __restrict__ Cf, unsigned short* __restrict__ Cb,
                                               int N, int dogelu, int resMask) {
    size_t i4 = ((size_t)blockIdx.x * 256 + threadIdx.x) * 4;
    int row = (int)(i4 / N), col = (int)(i4 % N);
    float4 acc = *(const float4*)(part + i4);
    for (int s = 1; s < S; ++s) {
        float4 p = *(const float4*)(part + (size_t)s * pstride + i4);
        acc.x += p.x; acc.y += p.y; acc.z += p.z; acc.w += p.w;
    }
    if (bias) {
        float4 bv = *(const float4*)(bias + col);
        acc.x += bv.x; acc.y += bv.y; acc.z += bv.z; acc.w += bv.w;
    }
    if (dogelu) {
        acc.x = fgelu(acc.x);
        acc.y = fgelu(acc.y);
        acc.z = fgelu(acc.z);
        acc.w = fgelu(acc.w);
    }
    if (res) {
        float4 rv = *(const float4*)(res + (size_t)(row & resMask) * N + col);
        acc.x += rv.x; acc.y += rv.y; acc.z += rv.z; acc.w += rv.w;
    }
    if (Cf) *(float4*)(Cf + i4) = acc;
    if (Cb) {
        uint2 o;
        o.x = (unsigned)f2bf(acc.x) | ((unsigned)f2bf(acc.y) << 16);
        o.y = (unsigned)f2bf(acc.z) | ((unsigned)f2bf(acc.w) << 16);
        *(uint2*)(Cb + i4) = o;
    }
}

// ---------------- split-K reduce + residual + fused LayerNorm (row per block) ----------------
__global__ __launch_bounds__(256) void redln_k(const float* __restrict__ part, int S, long long pstride,
                                               const float* __restrict__ bias,
                                               const float* __restrict__ res, int resMask,
                                               float* __restrict__ hout, unsigned short* __restrict__ ybf,
                                               const float* __restrict__ lns, const float* __restrict__ lnb,
                                               int N) {
    __shared__ float rs[4], rq[4];
    int row = blockIdx.x, t = threadIdx.x;
    float vbuf[3];
    float s1 = 0.f, s2 = 0.f;
    int nc = 0;
    for (int c = t; c < N; c += 256, ++nc) {
        size_t idx = (size_t)row * N + c;
        float a = part[idx];
        for (int s = 1; s < S; ++s) a += part[(size_t)s * pstride + idx];
        if (bias) a += bias[c];
        if (res) a += res[(size_t)(row & resMask) * N + c];
        if (hout) hout[idx] = a;
        vbuf[nc] = a;
        s1 += a; s2 += a * a;
    }
    if (lns) {
        for (int o = 32; o; o >>= 1) { s1 += __shfl_xor(s1, o); s2 += __shfl_xor(s2, o); }
        if ((t & 63) == 0) { rs[t >> 6] = s1; rq[t >> 6] = s2; }
        __syncthreads();
        s1 = rs[0] + rs[1] + rs[2] + rs[3];
        s2 = rq[0] + rq[1] + rq[2] + rq[3];
        float mean = s1 / N;
        float inv = rsqrtf(s2 / N - mean * mean + 1e-5f);
        nc = 0;
        for (int c = t; c < N; c += 256, ++nc)
            ybf[(size_t)row * N + c] = f2bf((vbuf[nc] - mean) * inv * lns[c] + lnb[c]);
    } else if (ybf) {
        nc = 0;
        for (int c = t; c < N; c += 256, ++nc)
            ybf[(size_t)row * N + c] = f2bf(vbuf[nc]);
    }
}

// ---------------- fused flash attention (bf16 MFMA) ----------------
__global__ __launch_bounds__(256) void fattn_k(
    const unsigned short* __restrict__ Qp, const unsigned short* __restrict__ Kp,
    const unsigned short* __restrict__ Vp, unsigned short* __restrict__ Op,
    int q_rstride, int kv_rstride, int o_rstride, int Sq, int Sk, int nh,
    float scale, const int* __restrict__ blk) {
    __shared__ unsigned short lK[64 * 64];
    __shared__ unsigned short lV[64 * 64];
    __shared__ unsigned short lP[4][16 * 64];
    const int t = threadIdx.x, wv = t >> 6, ln = t & 63;
    const int bh = blockIdx.x, b = bh / nh, hh = bh % nh;
    const int q0 = blockIdx.y * 64;
    const int tq = q0 >> 7;
    const int cl = ln & 15, rg = ln >> 4;

    bf16x8 qa[2];
    {
        const unsigned short* qrow = Qp + (size_t)(b * Sq + q0 + wv * 16 + cl) * q_rstride + hh * 64 + rg * 8;
        qa[0] = *(const bf16x8*)(qrow);
        qa[1] = *(const bf16x8*)(qrow + 32);
    }
    f32x4 oacc[4] = {};
    float mrow[4] = {-1e30f, -1e30f, -1e30f, -1e30f};
    float lrow[4] = {0.f, 0.f, 0.f, 0.f};

    int krr[2], kcc[2];
#pragma unroll
    for (int u = 0; u < 2; ++u) {
        int ch = u * 256 + t;
        krr[u] = ch >> 3;
        kcc[u] = ((ch & 7) ^ (krr[u] & 7)) << 3;
    }
    const int vk0 = (t >> 4) * 4, vd0 = (t & 15) * 4;

    for (int kc = 0; kc < Sk; kc += 64) {
        if (blk && blk[tq * 4 + (kc >> 7)]) continue;
        __syncthreads();
#pragma unroll
        for (int u = 0; u < 2; ++u)
            GLDS(Kp + (size_t)(b * Sk + kc + krr[u]) * kv_rstride + hh * 64 + kcc[u],
                 (char*)lK + ((u * 256 + wv * 64) << 4));
        {
            unsigned short a0[4], a1[4], a2[4], a3[4];
            const unsigned short* s0 = Vp + (size_t)(b * Sk + kc + vk0 + 0) * kv_rstride + hh * 64 + vd0;
            const unsigned short* s1 = Vp + (size_t)(b * Sk + kc + vk0 + 1) * kv_rstride + hh * 64 + vd0;
            const unsigned short* s2 = Vp + (size_t)(b * Sk + kc + vk0 + 2) * kv_rstride + hh * 64 + vd0;
            const unsigned short* s3 = Vp + (size_t)(b * Sk + kc + vk0 + 3) * kv_rstride + hh * 64 + vd0;
            *(uint2*)a0 = *(const uint2*)s0;
            *(uint2*)a1 = *(const uint2*)s1;
            *(uint2*)a2 = *(const uint2*)s2;
            *(uint2*)a3 = *(const uint2*)s3;
#pragma unroll
            for (int j = 0; j < 4; ++j) {
                int d = vd0 + j;
                int slot = (vk0 >> 3) ^ ((d + (d >> 3)) & 7);
                unsigned short pk[4] = {a0[j], a1[j], a2[j], a3[j]};
                *(uint2*)&lV[d * 64 + (slot << 3) + (vk0 & 7)] = *(uint2*)pk;
            }
        }
        __syncthreads();

        f32x4 sacc[4] = {};
#pragma unroll
        for (int kk = 0; kk < 2; ++kk)
#pragma unroll
            for (int f = 0; f < 4; ++f) {
                int rk = f * 16 + cl;
                bf16x8 kb = *(const bf16x8*)&lK[rk * 64 + (((kk * 4 + rg) ^ (rk & 7)) << 3)];
                sacc[f] = __builtin_amdgcn_mfma_f32_16x16x32_bf16(qa[kk], kb, sacc[f], 0, 0, 0);
            }
        float cm[4] = {-1e30f, -1e30f, -1e30f, -1e30f};
#pragma unroll
        for (int f = 0; f < 4; ++f)
#pragma unroll
            for (int r = 0; r < 4; ++r) {
                float v = sacc[f][r] * scale;
                sacc[f][r] = v;
                cm[r] = fmaxf(cm[r], v);
            }
#pragma unroll
        for (int o = 8; o; o >>= 1)
#pragma unroll
            for (int r = 0; r < 4; ++r) cm[r] = fmaxf(cm[r], __shfl_xor(cm[r], o));
        float corr[4], rsum[4];
#pragma unroll
        for (int r = 0; r < 4; ++r) {
            float nm = fmaxf(mrow[r], cm[r]);
            corr[r] = __expf(mrow[r] - nm);
            mrow[r] = nm;
            rsum[r] = 0.f;
        }
#pragma unroll
        for (int f = 0; f < 4; ++f)
#pragma unroll
            for (int r = 0; r < 4; ++r) {
                float p = __expf(sacc[f][r] - mrow[r]);
                sacc[f][r] = p;
                rsum[r] += p;
            }
#pragma unroll
        for (int o = 8; o; o >>= 1)
#pragma unroll
            for (int r = 0; r < 4; ++r) rsum[r] += __shfl_xor(rsum[r], o);
#pragma unroll
        for (int r = 0; r < 4; ++r) lrow[r] = lrow[r] * corr[r] + rsum[r];
#pragma unroll
        for (int f = 0; f < 4; ++f)
#pragma unroll
            for (int r = 0; r < 4; ++r) oacc[f][r] *= corr[r];
#pragma unroll
        for (int f = 0; f < 4; ++f)
#pragma unroll
            for (int r = 0; r < 4; ++r) {
                int q = rg * 4 + r, key = f * 16 + cl;
                lP[wv][q * 64 + (((key >> 3) ^ (q & 7)) << 3) + (key & 7)] = f2bf(sacc[f][r]);
            }
#pragma unroll
        for (int kk = 0; kk < 2; ++kk) {
            bf16x8 pa = *(const bf16x8*)&lP[wv][cl * 64 + (((kk * 4 + rg) ^ (cl & 7)) << 3)];
#pragma unroll
            for (int f = 0; f < 4; ++f) {
                int d = f * 16 + cl;
                bf16x8 vb = *(const bf16x8*)&lV[d * 64 + (((kk * 4 + rg) ^ ((d + (d >> 3)) & 7)) << 3)];
                oacc[f] = __builtin_amdgcn_mfma_f32_16x16x32_bf16(pa, vb, oacc[f], 0, 0, 0);
            }
        }
    }

    float inv[4];
#pragma unroll
    for (int r = 0; r < 4; ++r) inv[r] = 1.f / lrow[r];
#pragma unroll
    for (int f = 0; f < 4; ++f)
#pragma unroll
        for (int r = 0; r < 4; ++r) {
            int q = q0 + wv * 16 + rg * 4 + r;
            int d = f * 16 + cl;
            Op[(size_t)(b * Sq + q) * o_rstride + hh * 64 + d] = f2bf(oacc[f][r] * inv[r]);
        }
}

// ---------------- host helpers ----------------
static inline void launch_gemm(hipStream_t stream, const unsigned short* A, const unsigned short* Bt,
                               const float* bias, const float* res, float* Cf, unsigned short* Cb,
                               int M, int N, int K, int dogelu, int resMask = -1, int Z = 1,
                               long long aBS = 0, long long bBS = 0, long long cBS = 0, long long biasBS = 0) {
    hipLaunchKernelGGL(mgemm_k, dim3(N / 128, M / 128, Z), dim3(256), 0, stream,
                       A, Bt, bias, res, Cf, Cb, N, K, K, dogelu, resMask, aBS, bBS, cBS, biasBS);
}

static inline void gemm_part(hipStream_t stream, const unsigned short* A, const unsigned short* Bt,
                             float* part, int M, int N, int K, int S) {
    int Klen = K / S;
    hipLaunchKernelGGL(mgemm_k, dim3(N / 128, M / 128, S), dim3(256), 0, stream,
                       A, Bt, (const float*)nullptr, (const float*)nullptr, part, (unsigned short*)nullptr,
                       N, K, Klen, 0, -1, (long long)Klen, (long long)Klen, (long long)M * N, 0LL);
}

static inline void gemm_splitk(hipStream_t stream, const unsigned short* A, const unsigned short* Bt,
                               float* part, int M, int N, int K, int S,
                               const float* bias, const float* res, float* Cf, unsigned short* Cb,
                               int dogelu, int resMask = -1) {
    gemm_part(stream, A, Bt, part, M, N, K, S);
    hipLaunchKernelGGL(redep_k, dim3((unsigned)((size_t)M * N / 1024)), dim3(256), 0, stream,
                       part, S, (long long)M * N, bias, res, Cf, Cb, N, dogelu, resMask);
}

static inline void gemm_splitk_ln(hipStream_t stream, const unsigned short* A, const unsigned short* Bt,
                                  float* part, int M, int N, int K, int S,
                                  const float* bias, const float* res, int resMask,
                                  float* hout, unsigned short* ybf,
                                  const float* lns, const float* lnb) {
    gemm_part(stream, A, Bt, part, M, N, K, S);
    hipLaunchKernelGGL(redln_k, dim3(M), dim3(256), 0, stream,
                       part, S, (long long)M * N, bias, res, resMask, hout, ybf, lns, lnb, N);
}

extern "C" void kernel_launch(void* const* d_in, const int* in_sizes, int n_in,
                              void* d_out, int out_size, void* d_ws, size_t ws_size,
                              hipStream_t stream) {
    (void)in_sizes; (void)n_in; (void)out_size; (void)ws_size;
    const float* x          = (const float*)d_in[0];
    const float* mask_rand  = (const float*)d_in[1];
    const float* conv_w     = (const float*)d_in[2];
    const float* conv_b     = (const float*)d_in[3];
    const float* pos_emb    = (const float*)d_in[4];
    const float* enc_ln1_s  = (const float*)d_in[5];
    const float* enc_ln1_b  = (const float*)d_in[6];
    const float* enc_qkv_w  = (const float*)d_in[7];
    const float* enc_proj_w = (const float*)d_in[8];
    const float* enc_proj_b = (const float*)d_in[9];
    const float* enc_ln2_s  = (const float*)d_in[10];
    const float* enc_ln2_b  = (const float*)d_in[11];
    const float* enc_mlp_w1 = (const float*)d_in[12];
    const float* enc_mlp_b1 = (const float*)d_in[13];
    const float* enc_mlp_w2 = (const float*)d_in[14];
    const float* enc_mlp_b2 = (const float*)d_in[15];
    const float* e2d_w      = (const float*)d_in[16];
    const float* e2d_b      = (const float*)d_in[17];
    const float* dec_query  = (const float*)d_in[18];
    const float* dec_ln1_s  = (const float*)d_in[19];
    const float* dec_ln1_b  = (const float*)d_in[20];
    const float* dec_qkv_w  = (const float*)d_in[21];
    const float* dec_qkv_b  = (const float*)d_in[22];
    const float* dec_out_w  = (const float*)d_in[23];
    const float* dec_out_b  = (const float*)d_in[24];
    const float* dec_ln2_s  = (const float*)d_in[25];
    const float* dec_ln2_b  = (const float*)d_in[26];
    const float* dec_mlp_w1 = (const float*)d_in[27];
    const float* dec_mlp_b1 = (const float*)d_in[28];
    const float* dec_mlp_w2 = (const float*)d_in[29];
    const float* dec_mlp_b2 = (const float*)d_in[30];
    const float* head_ln_s  = (const float*)d_in[31];
    const float* head_ln_b  = (const float*)d_in[32];
    const float* head_w     = (const float*)d_in[33];
    const float* head_b     = (const float*)d_in[34];
    float* outp = (float*)d_out;

    // ---- workspace layout (float units) ----
    float* w = (float*)d_ws;
    size_t off = 0;
    int* blockedp = (int*)w; off += 128;
    float* h_buf = w + off; off += (size_t)4096 * 768;
    unsigned short* y_bf = (unsigned short*)(w + off); off += (size_t)4096 * 768 / 2;
    unsigned short* qkv_bf = (unsigned short*)(w + off); off += (size_t)4096 * 2304 / 2;
    unsigned short* mlp_bf = (unsigned short*)(w + off); off += (size_t)4096 * 3072 / 2;
    unsigned short* mem_bf = (unsigned short*)(w + off); off += (size_t)4096 * 512 / 2;
    float* dq_buf = w + off; off += (size_t)1024 * 512;
    unsigned short* R = (unsigned short*)(w + off); off += (size_t)16777216 / 2;  // 33.5 MB region
    unsigned short* decQkvT = (unsigned short*)(w + off); off += (size_t)12 * 262144 / 2;
    unsigned short* decOutT = (unsigned short*)(w + off); off += (size_t)4 * 262144 / 2;
    unsigned short* decMlp1T = (unsigned short*)(w + off); off += (size_t)4 * 1048576 / 2;
    unsigned short* decMlp2T = (unsigned short*)(w + off); off += (size_t)4 * 1048576 / 2;
    unsigned short* e2dT = (unsigned short*)(w + off); off += (size_t)393216 / 2;
    unsigned short* headT = (unsigned short*)(w + off); off += (size_t)393216 / 2;
    float* part_buf = w + off; off += (size_t)4 * 4096 * 768;  // split-K partials

    unsigned short* convW_bf = R;
    unsigned short* wqkvT = R;
    unsigned short* wprojT = R + (size_t)1769472;
    unsigned short* wmlp1T = R + (size_t)2359296;
    unsigned short* wmlp2T = R + (size_t)4718592;
    unsigned short* KdAll = R;
    unsigned short* VdAll = R + (size_t)8388608;

    unsigned short* xf_bf = mlp_bf;
    const float* fnull = nullptr;
    float* f32null = nullptr;
    unsigned short* bfnull = nullptr;
    const float scale = 0.125f;

    // ---- upfront prep ----
    hipLaunchKernelGGL(mask_k, dim3(1), dim3(128), 0, stream, mask_rand, blockedp);
    hipLaunchKernelGGL(wtrans_k, dim3(16, 16, 12), dim3(256), 0, stream, dec_qkv_w, decQkvT, 512, 512);
    hipLaunchKernelGGL(wtrans_k, dim3(16, 16, 4), dim3(256), 0, stream, dec_out_w, decOutT, 512, 512);
    hipLaunchKernelGGL(wtrans_k, dim3(64, 16, 4), dim3(256), 0, stream, dec_mlp_w1, decMlp1T, 512, 2048);
    hipLaunchKernelGGL(wtrans_k, dim3(16, 64, 4), dim3(256), 0, stream, dec_mlp_w2, decMlp2T, 2048, 512);
    hipLaunchKernelGGL(wtrans_k, dim3(16, 24, 1), dim3(256), 0, stream, e2d_w, e2dT, 768, 512);
    hipLaunchKernelGGL(wtrans_k, dim3(24, 16, 1), dim3(256), 0, stream, head_w, headT, 512, 768);
    hipLaunchKernelGGL(cast_k, dim3((768 * 3072 / 4 + 255) / 256), dim3(256), 0, stream,
                       conv_w, convW_bf, 768 * 3072 / 4);
    hipLaunchKernelGGL(gather_k, dim3(12288), dim3(256), 0, stream, x, xf_bf);
    // patchify (split-K 4) + bias + pos_emb + fused LN1(layer 0)
    gemm_splitk_ln(stream, xf_bf, convW_bf, part_buf, 4096, 768, 3072, 4,
                   conv_b, pos_emb, 511, h_buf, y_bf, enc_ln1_s, enc_ln1_b);

    // -------- encoder --------
    for (int l = 0; l < L_; ++l) {
        const int* blk = blockedp + l * 16;
        hipLaunchKernelGGL(wtransenc_k, dim3(6912), dim3(256), 0, stream,
                           enc_qkv_w + (size_t)l * 768 * 2304, enc_proj_w + (size_t)l * 768 * 768,
                           enc_mlp_w1 + (size_t)l * 768 * 3072, enc_mlp_w2 + (size_t)l * 3072 * 768,
                           wqkvT, wprojT, wmlp1T, wmlp2T);
        launch_gemm(stream, y_bf, wqkvT, fnull, fnull, f32null, qkv_bf, 4096, 2304, 768, 0);
        hipLaunchKernelGGL(fattn_k, dim3(B_ * NH_, S_ / 64), dim3(256), 0, stream,
                           qkv_bf, qkv_bf + 768, qkv_bf + 1536, y_bf,
                           2304, 2304, 768, S_, S_, NH_, scale, blk);
        // proj: split-K 2, res=h, fused LN2 -> y_bf
        gemm_splitk_ln(stream, y_bf, wprojT, part_buf, 4096, 768, 768, 2,
                       enc_proj_b + l * 768, h_buf, -1, h_buf, y_bf,
                       enc_ln2_s + l * 768, enc_ln2_b + l * 768);
        launch_gemm(stream, y_bf, wmlp1T, enc_mlp_b1 + l * 3072, fnull, f32null, mlp_bf, 4096, 3072, 768, 1);
        // mlp2: split-K 4, res=h, fused next-LN1 (raw cast on last layer)
        gemm_splitk_ln(stream, mlp_bf, wmlp2T, part_buf, 4096, 768, 3072, 4,
                       enc_mlp_b2 + l * 768, h_buf, -1, h_buf, y_bf,
                       (l < L_ - 1) ? (enc_ln1_s + (l + 1) * 768) : fnull,
                       (l < L_ - 1) ? (enc_ln1_b + (l + 1) * 768) : fnull);
    }

    // -------- enc2dec --------
    gemm_splitk(stream, y_bf, e2dT, part_buf, 4096, 512, 768, 2,
                e2d_b, fnull, f32null, mem_bf, 0);
    hipLaunchKernelGGL(dqinitln_k, dim3(1024), dim3(256), 0, stream,
                       dq_buf, y_bf, dec_query, dec_ln1_s, dec_ln1_b);
    launch_gemm(stream, mem_bf, decQkvT + (size_t)262144, dec_qkv_b + 512, fnull, f32null, KdAll,
                4096, 512, 512, 0, -1, 4, 0, 3LL * 262144, 4096LL * 512, 3LL * 512);
    launch_gemm(stream, mem_bf, decQkvT + (size_t)2 * 262144, dec_qkv_b + 2 * 512, fnull, f32null, VdAll,
                4096, 512, 512, 0, -1, 4, 0, 3LL * 262144, 4096LL * 512, 3LL * 512);

    // -------- decoder --------
    unsigned short* Qd = qkv_bf;
    for (int l = 0; l < LD_; ++l) {
        unsigned short* Kd = KdAll + (size_t)l * 4096 * 512;
        unsigned short* Vd = VdAll + (size_t)l * 4096 * 512;
        gemm_splitk(stream, y_bf, decQkvT + (size_t)(l * 3) * 262144, part_buf, 1024, 512, 512, 4,
                    dec_qkv_b + (l * 3) * 512, fnull, f32null, Qd, 0);
        hipLaunchKernelGGL(fattn_k, dim3(B_ * NHD_, P_ / 64), dim3(256), 0, stream,
                           Qd, Kd, Vd, y_bf, 512, 512, 512, P_, S_, NHD_, scale, (const int*)nullptr);
        // out: split-K 4, res=dq, fused LN2 -> y_bf
        gemm_splitk_ln(stream, y_bf, decOutT + (size_t)l * 262144, part_buf, 1024, 512, 512, 4,
                       dec_out_b + l * 512, dq_buf, -1, dq_buf, y_bf,
                       dec_ln2_s + l * 512, dec_ln2_b + l * 512);
        gemm_splitk(stream, y_bf, decMlp1T + (size_t)l * 1048576, part_buf, 1024, 2048, 512, 2,
                    dec_mlp_b1 + l * 2048, fnull, f32null, mlp_bf, 1);
        // mlp2: split-K 8, res=dq, fused next-LN1 (head_ln on last)
        gemm_splitk_ln(stream, mlp_bf, decMlp2T + (size_t)l * 1048576, part_buf, 1024, 512, 2048, 8,
                       dec_mlp_b2 + l * 512, dq_buf, -1, dq_buf, y_bf,
                       (l < LD_ - 1) ? (dec_ln1_s + (l + 1) * 512) : head_ln_s,
                       (l < LD_ - 1) ? (dec_ln1_b + (l + 1) * 512) : head_ln_b);
    }

    // -------- head --------
    gemm_splitk(stream, y_bf, headT, part_buf, 1024, 768, 512, 4,
                head_b, fnull, outp, bfnull, 0);
}